// Round 9
// baseline (4784.965 us; speedup 1.0000x reference)
//
#include <hip/hip_runtime.h>
#include <hip/hip_bf16.h>
#include <math.h>

// ---------------------------------------------------------------------------
// DepthlessTransformer forward. Round 9 = round 7 (proven, 3011us, absmax
// 0.015625) + ONE isolated change: GEMM LDS staging switched from
// global_load_lds (forces packed [128][32] rows -> 16-way read bank conflict,
// 2.43M counts) to register-staged writes into a +4-padded layout (LDP=36
// floats/row, 16B aligned). Read banks now spread uniformly (start =
// (4*fr + 8*fq) % 32). No XOR swizzle, no GLDS semantics -- every line
// inspection-verifiable. Round-8's 4-change bundle (failed, absmax 4.66) is
// fully reverted.
// D=512 H=8 DH=64 DI=512 L=6 NEX=6 FFI=1365 V=32000 B=2 N=192
// ---------------------------------------------------------------------------

#define EPSV 1.1920929e-07f
typedef __hip_bfloat16 bf16;
typedef __attribute__((ext_vector_type(4))) float f32x4;
typedef __attribute__((ext_vector_type(8))) short bf16x8;

__device__ inline void split8(const float* p, bf16x8& h8, bf16x8& l8) {
  f32x4 x0 = *(const f32x4*)(p);
  f32x4 x1 = *(const f32x4*)(p + 4);
#pragma unroll
  for (int i = 0; i < 4; ++i) {
    bf16 h0 = __float2bfloat16(x0[i]);
    bf16 l0 = __float2bfloat16(x0[i] - __bfloat162float(h0));
    h8[i] = __builtin_bit_cast(short, h0);
    l8[i] = __builtin_bit_cast(short, l0);
    bf16 h1 = __float2bfloat16(x1[i]);
    bf16 l1 = __float2bfloat16(x1[i] - __bfloat162float(h1));
    h8[i + 4] = __builtin_bit_cast(short, h1);
    l8[i + 4] = __builtin_bit_cast(short, l1);
  }
}

// ============== split-on-read GEMM: C = A * W^T (+bias), fp32 in/out =======
// A: [M,K] fp32 (batch stride aStr); W: [Nt,K] fp32 (batch stride wStr),
// Nt = N rounded up to 128 rows readable. C: [M,ldc] fp32. K % 32 == 0.
// LDS rows padded to 36 floats (144B, 16B-aligned) -> balanced banks.
// mode 0: plain (+optional bias). mode 1: GEGLU fused -- W rows interleaved
// (2c=sim_c, 2c+1=gate_c), writes act[row][col>>1] = z_sim*gelu(z_gate).
#define BM 128
#define BN 128
#define BKG 32
#define LDP 36
__global__ __launch_bounds__(256) void gemm_f32split_kernel(
    const float* __restrict__ A, const float* __restrict__ W,
    const float* __restrict__ bias, float* __restrict__ C,
    int M, int N, int K, int ldc,
    long long aStr, long long wStr, long long bStr, long long cStr, int mode)
{
  int batch = blockIdx.z;
  A += (size_t)batch * aStr;
  W += (size_t)batch * wStr;
  C += (size_t)batch * cStr;
  if (bias) bias += (size_t)batch * bStr;
  int m0 = blockIdx.y * BM, n0 = blockIdx.x * BN;

  __shared__ float As[BM * LDP];   // 18,432 B
  __shared__ float Ws[BN * LDP];   // 18,432 B

  int t = threadIdx.x;
  int wave = t >> 6, lane = t & 63;
  int wr = wave >> 1, wc = wave & 1;       // wave's 64x64 quadrant
  int fr = lane & 15, fq = lane >> 4;      // fragment row + k-group

  f32x4 acc[4][4] = {};

  for (int k0 = 0; k0 < K; k0 += BKG) {
    // ---- stage A and W tiles: 1024 16B-chunks each, 4 per thread ----
#pragma unroll
    for (int c = 0; c < 4; ++c) {
      int idx = c * 256 + t;            // 0..1023
      int row = idx >> 3;               // 0..127
      int col = (idx & 7) * 4;          // 0,4,...,28
      f32x4 av = *(const f32x4*)(A + (size_t)(m0 + row) * K + k0 + col);
      *(f32x4*)(&As[row * LDP + col]) = av;
      f32x4 wv = *(const f32x4*)(W + (size_t)(n0 + row) * K + k0 + col);
      *(f32x4*)(&Ws[row * LDP + col]) = wv;
    }
    __syncthreads();
    bf16x8 ah[4], al[4], wh[4], wl[4];
#pragma unroll
    for (int m = 0; m < 4; ++m)
      split8(&As[(wr * 64 + m * 16 + fr) * LDP + fq * 8], ah[m], al[m]);
#pragma unroll
    for (int n = 0; n < 4; ++n)
      split8(&Ws[(wc * 64 + n * 16 + fr) * LDP + fq * 8], wh[n], wl[n]);
#pragma unroll
    for (int m = 0; m < 4; ++m)
#pragma unroll
      for (int n = 0; n < 4; ++n) {
        acc[m][n] = __builtin_amdgcn_mfma_f32_16x16x32_bf16(ah[m], wh[n], acc[m][n], 0, 0, 0);
        acc[m][n] = __builtin_amdgcn_mfma_f32_16x16x32_bf16(al[m], wh[n], acc[m][n], 0, 0, 0);
        acc[m][n] = __builtin_amdgcn_mfma_f32_16x16x32_bf16(ah[m], wl[n], acc[m][n], 0, 0, 0);
      }
    __syncthreads();
  }

  if (mode == 0) {
#pragma unroll
    for (int m = 0; m < 4; ++m)
#pragma unroll
      for (int n = 0; n < 4; ++n) {
        int col = n0 + wc * 64 + n * 16 + fr;
        if (col >= N) continue;
        float bv = bias ? bias[col] : 0.f;
#pragma unroll
        for (int j = 0; j < 4; ++j) {
          int row = m0 + wr * 64 + m * 16 + fq * 4 + j;
          if (row < M) C[(size_t)row * ldc + col] = acc[m][n][j] + bv;
        }
      }
  } else {
    // GEGLU: even col = sim, odd col = gate (interleaved weight rows).
#pragma unroll
    for (int m = 0; m < 4; ++m)
#pragma unroll
      for (int n = 0; n < 4; ++n) {
        int col = n0 + wc * 64 + n * 16 + fr;
        float bv = bias[col];
#pragma unroll
        for (int j = 0; j < 4; ++j) {
          float z = acc[m][n][j] + bv;
          float zn = __shfl_xor(z, 1);   // partner: sim<->gate
          if (!(col & 1) && col < N) {
            float g = zn;
            float a = z * (0.5f * g * (1.f + erff(g * 0.70710678118654752f)));
            int row = m0 + wr * 64 + m * 16 + fq * 4 + j;
            if (row < M) C[(size_t)row * ldc + (col >> 1)] = a;
          }
        }
      }
  }
}

// ====== FF-keys weight perm+pad: [6,2730,512] -> [6,2816,512] interleaved ==
__global__ void ffk_perm_kernel(const float* __restrict__ kw,
                                const float* __restrict__ kb,
                                float* __restrict__ wout, float* __restrict__ bout)
{
  size_t idx = (size_t)blockIdx.x * 256 + threadIdx.x;
  const size_t per = 2816ull * 512;
  if (idx < 6 * per) {
    int b = (int)(idx / per);
    size_t r2 = idx % per;
    int r = (int)(r2 >> 9), k = (int)(r2 & 511);
    float v = 0.f;
    if (r < 2730) {
      int c = (r >> 1) + (r & 1) * 1365;
      v = kw[((size_t)b * 2730 + c) * 512 + k];
    }
    wout[idx] = v;
  }
  if (idx < 6 * 2816) {
    int b = (int)(idx / 2816), r = (int)(idx % 2816);
    float v = 0.f;
    if (r < 2730) {
      int c = (r >> 1) + (r & 1) * 1365;
      v = kb[(size_t)b * 2730 + c];
    }
    bout[idx] = v;
  }
}

// ====== FF-vals weight pad: [6,512,1365] -> [6,512,1408] (K zero-pad) ======
__global__ void ffv_pad_kernel(const float* __restrict__ vw, float* __restrict__ wout)
{
  size_t idx = (size_t)blockIdx.x * 256 + threadIdx.x;
  const size_t total = 6ull * 512 * 1408;
  if (idx >= total) return;
  int k = (int)(idx % 1408);
  size_t nr = idx / 1408;   // b*512 + n
  wout[idx] = (k < 1365) ? vw[nr * 1365 + k] : 0.f;
}

// ================= rmsnorm over dim 512 (fp32 -> fp32) =====================
__global__ __launch_bounds__(256) void rmsnorm_kernel(
    const float* __restrict__ x, const float* __restrict__ w,
    float* __restrict__ out, int rows_per_w)
{
  int r = blockIdx.x;
  int t = threadIdx.x;
  const float* xr = x + (size_t)r * 512;
  float a = xr[t], b = xr[t + 256];
  float ss = a * a + b * b;
  for (int off = 32; off; off >>= 1) ss += __shfl_xor(ss, off);
  __shared__ float wsum[4];
  if ((t & 63) == 0) wsum[t >> 6] = ss;
  __syncthreads();
  float tot = wsum[0] + wsum[1] + wsum[2] + wsum[3];
  float rs = rsqrtf(tot * (1.f / 512.f) + EPSV);
  const float* wr = w + (size_t)(r / rows_per_w) * 512;
  out[(size_t)r * 512 + t] = a * rs * wr[t];
  out[(size_t)r * 512 + t + 256] = b * rs * wr[t + 256];
}

// ================= broadcast tokens -> toks[L] =============================
__global__ void bcast_kernel(const float* __restrict__ tokens, float* __restrict__ toks)
{
  size_t idx = (size_t)blockIdx.x * 256 + threadIdx.x;
  const size_t total = (size_t)6 * 2 * 192 * 512;
  if (idx >= total) return;
  toks[idx] = tokens[idx % ((size_t)2 * 192 * 512)];
}

// ================= block self-attention, LDS-staged K ======================
// grid (48, 8, 12), 256 threads = 4 waves; wave w handles query i = bx*4+w.
__global__ __launch_bounds__(256) void block_attn_kernel(
    const float* __restrict__ q, const float* __restrict__ kv, float* __restrict__ o)
{
  int h = blockIdx.y, lb = blockIdx.z;
  int t = threadIdx.x;
  int wave = t >> 6, lane = t & 63;
  int i = blockIdx.x * 4 + wave;

  __shared__ float Ks[192][65];   // 49,920 B
  __shared__ float qs[4][64];
  __shared__ float ps[4][192];

  const float* kb = kv + (size_t)lb * 192 * 1024 + h * 64;
#pragma unroll
  for (int c = 0; c < 48; ++c) {
    int idx = c * 256 + t;
    int row = idx >> 6, col = idx & 63;
    Ks[row][col] = kb[(size_t)row * 1024 + col];
  }
  const float* qrow = q + ((size_t)(lb * 192 + i)) * 512 + h * 64;
  qs[wave][lane] = qrow[lane];
  __syncthreads();

  float s[3];
#pragma unroll
  for (int r = 0; r < 3; ++r) {
    int j = lane + r * 64;
    float acc = 0.f;
#pragma unroll 8
    for (int d = 0; d < 64; ++d) acc += qs[wave][d] * Ks[j][d];
    s[r] = acc;
  }
  float mx = fmaxf(fmaxf(s[0], s[1]), s[2]);
  for (int off = 32; off; off >>= 1) mx = fmaxf(mx, __shfl_xor(mx, off));
  float sum = 0.f;
#pragma unroll
  for (int r = 0; r < 3; ++r) { s[r] = expf(s[r] - mx); sum += s[r]; }
  for (int off = 32; off; off >>= 1) sum += __shfl_xor(sum, off);
  float inv = 1.f / sum;
#pragma unroll
  for (int r = 0; r < 3; ++r) ps[wave][lane + r * 64] = s[r] * inv;
  const float* vb = kb + 512;
  float acc = 0.f;
  for (int j = 0; j < 192; ++j) acc += ps[wave][j] * vb[(size_t)j * 1024 + lane];
  o[((size_t)(lb * 192 + i)) * 512 + h * 64 + lane] = acc;
}

// ================= pooled attention, K/V amortized over 6 queries ==========
__global__ __launch_bounds__(64) void pooled_attn_kernel(
    const float* __restrict__ q, const float* __restrict__ Kc,
    const float* __restrict__ Vc, float* __restrict__ o, int M, int mode)
{
  int n = blockIdx.x, h = blockIdx.y, z = blockIdx.z;
  int lane = threadIdx.x;
  int nq = mode ? 1 : 6;

  __shared__ float Ks[80][65];    // 20,800 B
  __shared__ float qs[6][64];
  __shared__ float p[6][128];

  for (int m = 0; m < M; ++m)
    Ks[m][lane] = Kc[(((size_t)m * 2 + z) * 192 + n) * 512 + h * 64 + lane];
  for (int jj = 0; jj < nq; ++jj) {
    const float* qrow = mode ? (q + h * 64)
                             : (q + ((size_t)((z * 6 + jj) * 192 + n)) * 512 + h * 64);
    qs[jj][lane] = qrow[lane];
  }
  __syncthreads();

  float d0[6] = {}, d1[6] = {};
  int m1 = lane + 64;
#pragma unroll 4
  for (int d = 0; d < 64; ++d) {
    float k0 = Ks[lane][d];
    float k1 = Ks[m1 & 79][d];
#pragma unroll
    for (int jj = 0; jj < 6; ++jj) {
      float qv = qs[jj][d];
      d0[jj] += qv * k0;
      d1[jj] += qv * k1;
    }
  }
  float acc[6] = {};
#pragma unroll
  for (int jj = 0; jj < 6; ++jj) {
    if (jj >= nq) break;
    float s0 = (lane < M) ? d0[jj] : -1e30f;
    float s1 = (m1 < M) ? d1[jj] : -1e30f;
    float mx = fmaxf(s0, s1);
    for (int off = 32; off; off >>= 1) mx = fmaxf(mx, __shfl_xor(mx, off));
    float e0 = (lane < M) ? expf(s0 - mx) : 0.f;
    float e1 = (m1 < M) ? expf(s1 - mx) : 0.f;
    float sum = e0 + e1;
    for (int off = 32; off; off >>= 1) sum += __shfl_xor(sum, off);
    float inv = 1.f / sum;
    p[jj][lane] = e0 * inv;
    p[jj][m1] = e1 * inv;
  }
  __syncthreads();

  for (int m = 0; m < M; ++m) {
    float v = Vc[(((size_t)m * 2 + z) * 192 + n) * 512 + h * 64 + lane];
#pragma unroll
    for (int jj = 0; jj < 6; ++jj) acc[jj] += p[jj][m] * v;
  }
#pragma unroll
  for (int jj = 0; jj < 6; ++jj) {
    if (jj >= nq) break;
    int orow = mode ? (z * 192 + n) : ((z * 6 + jj) * 192 + n);
    o[(size_t)orow * 512 + h * 64 + lane] = acc[jj];
  }
}

// ================= kv-cache fill (fp32, per-head key rmsnorm) ==============
__global__ __launch_bounds__(128) void cache_fill_kernel(
    const float* __restrict__ kvp, const float* __restrict__ knw,
    float* __restrict__ Kc, float* __restrict__ Vc, int base_e)
{
  int n = blockIdx.x;
  int t = blockIdx.y;
  int g = t >> 1, b = t & 1;
  int e = base_e + g;
  int lane = threadIdx.x;  // 128 lanes x 4 cols; 16 lanes per head
  const float* src = kvp + ((size_t)t * 192 + n) * 1024;
  float k4[4];
  float ss = 0.f;
#pragma unroll
  for (int u = 0; u < 4; ++u) { k4[u] = src[lane * 4 + u]; ss += k4[u] * k4[u]; }
  for (int off = 8; off; off >>= 1) ss += __shfl_xor(ss, off, 16);
  float rs = rsqrtf(ss * (1.f / 64.f) + EPSV);
  float* kd = Kc + (((size_t)e * 2 + b) * 192 + n) * 512;
  float* vd = Vc + (((size_t)e * 2 + b) * 192 + n) * 512;
#pragma unroll
  for (int u = 0; u < 4; ++u) {
    int c = lane * 4 + u;
    kd[c] = k4[u] * rs * knw[c & 63];
    vd[c] = src[512 + c];
  }
}

// ===========================================================================
extern "C" void kernel_launch(void* const* d_in, const int* in_sizes, int n_in,
                              void* d_out, int out_size, void* d_ws, size_t ws_size,
                              hipStream_t stream)
{
  const float* tokens   = (const float*)d_in[0];
  const float* attn_nw  = (const float*)d_in[1];
  const float* attn_qw  = (const float*)d_in[2];
  const float* attn_kvw = (const float*)d_in[3];
  const float* attn_ow  = (const float*)d_in[4];
  const float* ff_nw    = (const float*)d_in[5];
  const float* ff_kw    = (const float*)d_in[6];
  const float* ff_kb    = (const float*)d_in[7];
  const float* ff_vw    = (const float*)d_in[8];
  const float* ff_vb    = (const float*)d_in[9];
  const float* res_nw   = (const float*)d_in[10];
  const float* res_knw  = (const float*)d_in[11];
  const float* res_qw   = (const float*)d_in[12];
  const float* res_kvw  = (const float*)d_in[13];
  const float* res_ow   = (const float*)d_in[14];
  const float* q_ro     = (const float*)d_in[15];
  const float* ro_nw    = (const float*)d_in[16];
  const float* ro_w     = (const float*)d_in[17];
  float* out = (float*)d_out;

  // ---- workspace carve-up (54,281,728 floats = 217.1 MB) ----
  float* ws = (float*)d_ws;
  const size_t NEED = 54281728ull * 4ull;
  if (ws_size < NEED) return;
  float* ffk_w   = ws;  ws += 6ull * 2816 * 512;   // 8,650,752 (perm+pad fp32)
  float* ffk_b   = ws;  ws += 6ull * 2816;         // 16,896
  float* ffv_w   = ws;  ws += 6ull * 512 * 1408;   // 4,325,376 (K-pad fp32)
  float* toks    = ws;  ws += 1179648;             // [6,2,192,512]
  float* hbuf    = ws;  ws += 2359296;             // [<=4608,512]
  float* msgbuf  = ws;  ws += 2359296;             // [2,6,2,192,512]
  float* scratch = ws;  ws += 4718592;             // union region
  float* rqn     = ws;  ws += 512;
  float* rq      = ws;  ws += 512;
  float* Kc      = ws;  ws += 15335424;            // [78,2,192,512]
  float* Vc      = ws;  ws += 15335424;
  // scratch union (all uses strictly serialized on `stream`):
  float* qbuf   = scratch;                 // [2304,512]
  float* kvbuf  = scratch + 1179648;       // [12,192,1024]
  float* obuf   = scratch + 3538944;       // [2304,512]
  float* kvpool = scratch;                 // [<=24,192,1024] = 4,718,592
  float* act    = scratch;                 // [2304,1408] = 3,244,032
  // readout aliases (msgbuf dead by then):
  float* robuf  = msgbuf;                  // [384,512]
  float* robuf2 = msgbuf + 196608;         // [384,512]
  float* ronorm = msgbuf + 393216;         // [384,512]

  auto gemm = [&](const float* A, const float* W, const float* bias, float* C,
                  int M, int N, int K, int ldc,
                  long long aStr, long long wStr, long long bStr, long long cStr,
                  int nb, int mode) {
    dim3 g((N + BN - 1) / BN, (M + BM - 1) / BM, nb);
    hipLaunchKernelGGL(gemm_f32split_kernel, g, dim3(256), 0, stream,
                       A, W, bias, C, M, N, K, ldc, aStr, wStr, bStr, cStr, mode);
  };

  // ---- FF weight prep (perm+pad) ----
  hipLaunchKernelGGL(ffk_perm_kernel, dim3((unsigned)((6ull * 2816 * 512 + 255) / 256)),
                     dim3(256), 0, stream, ff_kw, ff_kb, ffk_w, ffk_b);
  hipLaunchKernelGGL(ffv_pad_kernel, dim3((unsigned)((6ull * 512 * 1408 + 255) / 256)),
                     dim3(256), 0, stream, ff_vw, ffv_w);

  // ---- init: toks = broadcast(tokens); cache msg0 kv entries 0..5 ----
  {
    const int total = 6 * 2 * 192 * 512;
    hipLaunchKernelGGL(bcast_kernel, dim3((total + 255) / 256), dim3(256), 0, stream,
                       tokens, toks);
  }
  hipLaunchKernelGGL(rmsnorm_kernel, dim3(2304), dim3(256), 0, stream,
                     toks, res_nw, hbuf, 2304);
  gemm(hbuf, res_kvw, nullptr, kvpool, 384, 1024, 512, 1024,
       196608, 0, 0, 393216, 6, 0);
  hipLaunchKernelGGL(cache_fill_kernel, dim3(192, 12), dim3(128), 0, stream,
                     kvpool, res_knw, Kc, Vc, 0);

  for (int it = 0; it < 6; ++it) {
    // ---- block self-attention -> msgbuf[0] ----
    hipLaunchKernelGGL(rmsnorm_kernel, dim3(2304), dim3(256), 0, stream,
                       toks, attn_nw, hbuf, 384);
    gemm(hbuf, attn_qw, nullptr, qbuf, 384, 512, 512, 512,
         196608, 262144, 0, 196608, 6, 0);
    gemm(hbuf, attn_kvw, nullptr, kvbuf, 384, 1024, 512, 1024,
         196608, 524288, 0, 393216, 6, 0);
    hipLaunchKernelGGL(block_attn_kernel, dim3(48, 8, 12), dim3(256), 0, stream,
                       qbuf, kvbuf, obuf);
    gemm(obuf, attn_ow, nullptr, msgbuf, 384, 512, 512, 512,
         196608, 262144, 0, 196608, 6, 0);
    // ---- GEGLU FF (fused) -> msgbuf[1] ----
    hipLaunchKernelGGL(rmsnorm_kernel, dim3(2304), dim3(256), 0, stream,
                       toks, ff_nw, hbuf, 384);
    gemm(hbuf, ffk_w, ffk_b, act, 384, 2730, 512, 1408,
         196608, 1441792, 2816, 540672, 6, 1);       // clobbers qbuf/kvbuf (dead)
    gemm(act, ffv_w, ff_vb, msgbuf + 1179648, 384, 512, 1408, 512,
         540672, 720896, 512, 196608, 6, 0);
    // ---- cache kv for the two new messages ----
    hipLaunchKernelGGL(rmsnorm_kernel, dim3(4608), dim3(256), 0, stream,
                       msgbuf, res_nw, hbuf, 4608);
    gemm(hbuf, res_kvw, nullptr, kvpool, 384, 1024, 512, 1024,
         196608, 0, 0, 393216, 12, 0);               // clobbers act (dead)
    hipLaunchKernelGGL(cache_fill_kernel, dim3(192, 24), dim3(128), 0, stream,
                       kvpool, res_knw, Kc, Vc, (2 * it + 1) * 6);
    if (it == 5) break;
    // ---- pooled cross-attention over all cached entries -> new toks ----
    hipLaunchKernelGGL(rmsnorm_kernel, dim3(2304), dim3(256), 0, stream,
                       toks, res_nw, hbuf, 2304);
    gemm(hbuf, res_qw, nullptr, qbuf, 2304, 512, 512, 512,
         0, 0, 0, 0, 1, 0);                          // clobbers kvpool (dead)
    hipLaunchKernelGGL(pooled_attn_kernel, dim3(192, 8, 2), dim3(64), 0, stream,
                       qbuf, Kc, Vc, obuf, (3 + 2 * it) * 6, 0);
    gemm(obuf, res_ow, nullptr, toks, 2304, 512, 512, 512,
         0, 0, 0, 0, 1, 0);
  }

  // ---- readout ----
  hipLaunchKernelGGL(rmsnorm_kernel, dim3(1), dim3(256), 0, stream,
                     q_ro, res_nw, rqn, 1);
  gemm(rqn, res_qw, nullptr, rq, 1, 512, 512, 512, 0, 0, 0, 0, 1, 0);
  hipLaunchKernelGGL(pooled_attn_kernel, dim3(192, 8, 2), dim3(64), 0, stream,
                     rq, Kc, Vc, robuf, 78, 1);
  gemm(robuf, res_ow, nullptr, robuf2, 384, 512, 512, 512, 0, 0, 0, 0, 1, 0);
  hipLaunchKernelGGL(rmsnorm_kernel, dim3(384), dim3(256), 0, stream,
                     robuf2, ro_nw, ronorm, 384);
  gemm(ronorm, ro_w, nullptr, out, 384, 32000, 512, 32000, 0, 0, 0, 0, 1, 0);
}

// Round 10
// 2867.603 us; speedup vs baseline: 1.6686x; 1.6686x over previous
//
#include <hip/hip_runtime.h>
#include <hip/hip_bf16.h>
#include <math.h>

// ---------------------------------------------------------------------------
// DepthlessTransformer forward. Round 10 = round 7 (proven, 3011us) with ONE
// kernel changed: the GEMM now splits fp32 -> hi/lo bf16 AT STAGING TIME and
// stores four bf16 LDS tiles (Ah/Al/Wh/Wl) with row pitch 40 bf16 (80B,
// 16B-aligned). Fragment-read bank start = (20*row + 4*fq)%32 -> 2-way max
// (vs r7's 16-way on packed fp32 rows, 2.43M conflict counts). Split VALU
// runs once per element (r7: per fragment read, ~4x redundant). RTN split
// math identical to r5-7 (proven absmax 0.015625).
// Round 9's padded-fp32 reg-staging (8-way WRITE conflicts, 4785us) reverted.
// D=512 H=8 DH=64 DI=512 L=6 NEX=6 FFI=1365 V=32000 B=2 N=192
// ---------------------------------------------------------------------------

#define EPSV 1.1920929e-07f
typedef __hip_bfloat16 bf16;
typedef __attribute__((ext_vector_type(4))) float f32x4;
typedef __attribute__((ext_vector_type(8))) short bf16x8;

// RTN split of 8 fp32 (two f32x4) into hi/lo bf16x8. Proven r5-7 numerics.
__device__ inline void split8r(f32x4 x0, f32x4 x1, bf16x8& h8, bf16x8& l8) {
#pragma unroll
  for (int i = 0; i < 4; ++i) {
    bf16 h0 = __float2bfloat16(x0[i]);
    h8[i] = __builtin_bit_cast(short, h0);
    l8[i] = __builtin_bit_cast(short, __float2bfloat16(x0[i] - __bfloat162float(h0)));
    bf16 h1 = __float2bfloat16(x1[i]);
    h8[i + 4] = __builtin_bit_cast(short, h1);
    l8[i + 4] = __builtin_bit_cast(short, __float2bfloat16(x1[i] - __bfloat162float(h1)));
  }
}

// ============== split-at-staging GEMM: C = A * W^T (+bias), fp32 in/out ====
// A: [M,K] fp32 (batch stride aStr); W: [Nt,K] fp32 (batch stride wStr),
// Nt = N rounded up to 128 rows readable. C: [M,ldc] fp32. K % 32 == 0.
// mode 0: plain (+optional bias). mode 1: GEGLU fused -- W rows interleaved
// (2c=sim_c, 2c+1=gate_c), writes act[row][col>>1] = z_sim*gelu(z_gate).
#define BM 128
#define BN 128
#define BKG 32
#define LDB 40   // bf16 row pitch: 80B, 16B-aligned, bank start (20r+4c)%32
__global__ __launch_bounds__(256) void gemm_f32split_kernel(
    const float* __restrict__ A, const float* __restrict__ W,
    const float* __restrict__ bias, float* __restrict__ C,
    int M, int N, int K, int ldc,
    long long aStr, long long wStr, long long bStr, long long cStr, int mode)
{
  int batch = blockIdx.z;
  A += (size_t)batch * aStr;
  W += (size_t)batch * wStr;
  C += (size_t)batch * cStr;
  if (bias) bias += (size_t)batch * bStr;
  int m0 = blockIdx.y * BM, n0 = blockIdx.x * BN;

  __shared__ short Ah[BM * LDB], Al[BM * LDB];   // 10,240 B each
  __shared__ short Wh[BN * LDB], Wl[BN * LDB];   // 40,960 B total

  int t = threadIdx.x;
  int wave = t >> 6, lane = t & 63;
  int wr = wave >> 1, wc = wave & 1;       // wave's 64x64 quadrant
  int fr = lane & 15, fq = lane >> 4;      // fragment row + k-group
  int srow = t >> 2;                       // staging rows srow, srow+64
  int scol = (t & 3) * 8;                  // float col 0,8,16,24

  f32x4 acc[4][4] = {};

  for (int k0 = 0; k0 < K; k0 += BKG) {
    // ---- stage: load fp32, split to bf16 hi/lo, ds_write both tiles ----
    {
      const float* pa0 = A + (size_t)(m0 + srow) * K + k0 + scol;
      const float* pa1 = A + (size_t)(m0 + srow + 64) * K + k0 + scol;
      const float* pw0 = W + (size_t)(n0 + srow) * K + k0 + scol;
      const float* pw1 = W + (size_t)(n0 + srow + 64) * K + k0 + scol;
      f32x4 a00 = *(const f32x4*)pa0, a01 = *(const f32x4*)(pa0 + 4);
      f32x4 a10 = *(const f32x4*)pa1, a11 = *(const f32x4*)(pa1 + 4);
      f32x4 w00 = *(const f32x4*)pw0, w01 = *(const f32x4*)(pw0 + 4);
      f32x4 w10 = *(const f32x4*)pw1, w11 = *(const f32x4*)(pw1 + 4);
      bf16x8 h, l;
      split8r(a00, a01, h, l);
      *(bf16x8*)&Ah[srow * LDB + scol] = h;
      *(bf16x8*)&Al[srow * LDB + scol] = l;
      split8r(a10, a11, h, l);
      *(bf16x8*)&Ah[(srow + 64) * LDB + scol] = h;
      *(bf16x8*)&Al[(srow + 64) * LDB + scol] = l;
      split8r(w00, w01, h, l);
      *(bf16x8*)&Wh[srow * LDB + scol] = h;
      *(bf16x8*)&Wl[srow * LDB + scol] = l;
      split8r(w10, w11, h, l);
      *(bf16x8*)&Wh[(srow + 64) * LDB + scol] = h;
      *(bf16x8*)&Wl[(srow + 64) * LDB + scol] = l;
    }
    __syncthreads();
    bf16x8 ah[4], al[4], wh[4], wl[4];
#pragma unroll
    for (int m = 0; m < 4; ++m) {
      int r = (wr * 64 + m * 16 + fr) * LDB + fq * 8;
      ah[m] = *(const bf16x8*)&Ah[r];
      al[m] = *(const bf16x8*)&Al[r];
    }
#pragma unroll
    for (int n = 0; n < 4; ++n) {
      int r = (wc * 64 + n * 16 + fr) * LDB + fq * 8;
      wh[n] = *(const bf16x8*)&Wh[r];
      wl[n] = *(const bf16x8*)&Wl[r];
    }
#pragma unroll
    for (int m = 0; m < 4; ++m)
#pragma unroll
      for (int n = 0; n < 4; ++n) {
        acc[m][n] = __builtin_amdgcn_mfma_f32_16x16x32_bf16(ah[m], wh[n], acc[m][n], 0, 0, 0);
        acc[m][n] = __builtin_amdgcn_mfma_f32_16x16x32_bf16(al[m], wh[n], acc[m][n], 0, 0, 0);
        acc[m][n] = __builtin_amdgcn_mfma_f32_16x16x32_bf16(ah[m], wl[n], acc[m][n], 0, 0, 0);
      }
    __syncthreads();
  }

  if (mode == 0) {
#pragma unroll
    for (int m = 0; m < 4; ++m)
#pragma unroll
      for (int n = 0; n < 4; ++n) {
        int col = n0 + wc * 64 + n * 16 + fr;
        if (col >= N) continue;
        float bv = bias ? bias[col] : 0.f;
#pragma unroll
        for (int j = 0; j < 4; ++j) {
          int row = m0 + wr * 64 + m * 16 + fq * 4 + j;
          if (row < M) C[(size_t)row * ldc + col] = acc[m][n][j] + bv;
        }
      }
  } else {
    // GEGLU: even col = sim, odd col = gate (interleaved weight rows).
#pragma unroll
    for (int m = 0; m < 4; ++m)
#pragma unroll
      for (int n = 0; n < 4; ++n) {
        int col = n0 + wc * 64 + n * 16 + fr;
        float bv = bias[col];
#pragma unroll
        for (int j = 0; j < 4; ++j) {
          float z = acc[m][n][j] + bv;
          float zn = __shfl_xor(z, 1);   // partner: sim<->gate
          if (!(col & 1) && col < N) {
            float g = zn;
            float a = z * (0.5f * g * (1.f + erff(g * 0.70710678118654752f)));
            int row = m0 + wr * 64 + m * 16 + fq * 4 + j;
            if (row < M) C[(size_t)row * ldc + (col >> 1)] = a;
          }
        }
      }
  }
}

// ====== FF-keys weight perm+pad: [6,2730,512] -> [6,2816,512] interleaved ==
__global__ void ffk_perm_kernel(const float* __restrict__ kw,
                                const float* __restrict__ kb,
                                float* __restrict__ wout, float* __restrict__ bout)
{
  size_t idx = (size_t)blockIdx.x * 256 + threadIdx.x;
  const size_t per = 2816ull * 512;
  if (idx < 6 * per) {
    int b = (int)(idx / per);
    size_t r2 = idx % per;
    int r = (int)(r2 >> 9), k = (int)(r2 & 511);
    float v = 0.f;
    if (r < 2730) {
      int c = (r >> 1) + (r & 1) * 1365;
      v = kw[((size_t)b * 2730 + c) * 512 + k];
    }
    wout[idx] = v;
  }
  if (idx < 6 * 2816) {
    int b = (int)(idx / 2816), r = (int)(idx % 2816);
    float v = 0.f;
    if (r < 2730) {
      int c = (r >> 1) + (r & 1) * 1365;
      v = kb[(size_t)b * 2730 + c];
    }
    bout[idx] = v;
  }
}

// ====== FF-vals weight pad: [6,512,1365] -> [6,512,1408] (K zero-pad) ======
__global__ void ffv_pad_kernel(const float* __restrict__ vw, float* __restrict__ wout)
{
  size_t idx = (size_t)blockIdx.x * 256 + threadIdx.x;
  const size_t total = 6ull * 512 * 1408;
  if (idx >= total) return;
  int k = (int)(idx % 1408);
  size_t nr = idx / 1408;   // b*512 + n
  wout[idx] = (k < 1365) ? vw[nr * 1365 + k] : 0.f;
}

// ================= rmsnorm over dim 512 (fp32 -> fp32) =====================
__global__ __launch_bounds__(256) void rmsnorm_kernel(
    const float* __restrict__ x, const float* __restrict__ w,
    float* __restrict__ out, int rows_per_w)
{
  int r = blockIdx.x;
  int t = threadIdx.x;
  const float* xr = x + (size_t)r * 512;
  float a = xr[t], b = xr[t + 256];
  float ss = a * a + b * b;
  for (int off = 32; off; off >>= 1) ss += __shfl_xor(ss, off);
  __shared__ float wsum[4];
  if ((t & 63) == 0) wsum[t >> 6] = ss;
  __syncthreads();
  float tot = wsum[0] + wsum[1] + wsum[2] + wsum[3];
  float rs = rsqrtf(tot * (1.f / 512.f) + EPSV);
  const float* wr = w + (size_t)(r / rows_per_w) * 512;
  out[(size_t)r * 512 + t] = a * rs * wr[t];
  out[(size_t)r * 512 + t + 256] = b * rs * wr[t + 256];
}

// ================= broadcast tokens -> toks[L] =============================
__global__ void bcast_kernel(const float* __restrict__ tokens, float* __restrict__ toks)
{
  size_t idx = (size_t)blockIdx.x * 256 + threadIdx.x;
  const size_t total = (size_t)6 * 2 * 192 * 512;
  if (idx >= total) return;
  toks[idx] = tokens[idx % ((size_t)2 * 192 * 512)];
}

// ================= block self-attention, LDS-staged K ======================
// grid (48, 8, 12), 256 threads = 4 waves; wave w handles query i = bx*4+w.
__global__ __launch_bounds__(256) void block_attn_kernel(
    const float* __restrict__ q, const float* __restrict__ kv, float* __restrict__ o)
{
  int h = blockIdx.y, lb = blockIdx.z;
  int t = threadIdx.x;
  int wave = t >> 6, lane = t & 63;
  int i = blockIdx.x * 4 + wave;

  __shared__ float Ks[192][65];   // 49,920 B
  __shared__ float qs[4][64];
  __shared__ float ps[4][192];

  const float* kb = kv + (size_t)lb * 192 * 1024 + h * 64;
#pragma unroll
  for (int c = 0; c < 48; ++c) {
    int idx = c * 256 + t;
    int row = idx >> 6, col = idx & 63;
    Ks[row][col] = kb[(size_t)row * 1024 + col];
  }
  const float* qrow = q + ((size_t)(lb * 192 + i)) * 512 + h * 64;
  qs[wave][lane] = qrow[lane];
  __syncthreads();

  float s[3];
#pragma unroll
  for (int r = 0; r < 3; ++r) {
    int j = lane + r * 64;
    float acc = 0.f;
#pragma unroll 8
    for (int d = 0; d < 64; ++d) acc += qs[wave][d] * Ks[j][d];
    s[r] = acc;
  }
  float mx = fmaxf(fmaxf(s[0], s[1]), s[2]);
  for (int off = 32; off; off >>= 1) mx = fmaxf(mx, __shfl_xor(mx, off));
  float sum = 0.f;
#pragma unroll
  for (int r = 0; r < 3; ++r) { s[r] = expf(s[r] - mx); sum += s[r]; }
  for (int off = 32; off; off >>= 1) sum += __shfl_xor(sum, off);
  float inv = 1.f / sum;
#pragma unroll
  for (int r = 0; r < 3; ++r) ps[wave][lane + r * 64] = s[r] * inv;
  const float* vb = kb + 512;
  float acc = 0.f;
  for (int j = 0; j < 192; ++j) acc += ps[wave][j] * vb[(size_t)j * 1024 + lane];
  o[((size_t)(lb * 192 + i)) * 512 + h * 64 + lane] = acc;
}

// ================= pooled attention, K/V amortized over 6 queries ==========
__global__ __launch_bounds__(64) void pooled_attn_kernel(
    const float* __restrict__ q, const float* __restrict__ Kc,
    const float* __restrict__ Vc, float* __restrict__ o, int M, int mode)
{
  int n = blockIdx.x, h = blockIdx.y, z = blockIdx.z;
  int lane = threadIdx.x;
  int nq = mode ? 1 : 6;

  __shared__ float Ks[80][65];    // 20,800 B
  __shared__ float qs[6][64];
  __shared__ float p[6][128];

  for (int m = 0; m < M; ++m)
    Ks[m][lane] = Kc[(((size_t)m * 2 + z) * 192 + n) * 512 + h * 64 + lane];
  for (int jj = 0; jj < nq; ++jj) {
    const float* qrow = mode ? (q + h * 64)
                             : (q + ((size_t)((z * 6 + jj) * 192 + n)) * 512 + h * 64);
    qs[jj][lane] = qrow[lane];
  }
  __syncthreads();

  float d0[6] = {}, d1[6] = {};
  int m1 = lane + 64;
#pragma unroll 4
  for (int d = 0; d < 64; ++d) {
    float k0 = Ks[lane][d];
    float k1 = Ks[m1 & 79][d];
#pragma unroll
    for (int jj = 0; jj < 6; ++jj) {
      float qv = qs[jj][d];
      d0[jj] += qv * k0;
      d1[jj] += qv * k1;
    }
  }
  float acc[6] = {};
#pragma unroll
  for (int jj = 0; jj < 6; ++jj) {
    if (jj >= nq) break;
    float s0 = (lane < M) ? d0[jj] : -1e30f;
    float s1 = (m1 < M) ? d1[jj] : -1e30f;
    float mx = fmaxf(s0, s1);
    for (int off = 32; off; off >>= 1) mx = fmaxf(mx, __shfl_xor(mx, off));
    float e0 = (lane < M) ? expf(s0 - mx) : 0.f;
    float e1 = (m1 < M) ? expf(s1 - mx) : 0.f;
    float sum = e0 + e1;
    for (int off = 32; off; off >>= 1) sum += __shfl_xor(sum, off);
    float inv = 1.f / sum;
    p[jj][lane] = e0 * inv;
    p[jj][m1] = e1 * inv;
  }
  __syncthreads();

  for (int m = 0; m < M; ++m) {
    float v = Vc[(((size_t)m * 2 + z) * 192 + n) * 512 + h * 64 + lane];
#pragma unroll
    for (int jj = 0; jj < 6; ++jj) acc[jj] += p[jj][m] * v;
  }
#pragma unroll
  for (int jj = 0; jj < 6; ++jj) {
    if (jj >= nq) break;
    int orow = mode ? (z * 192 + n) : ((z * 6 + jj) * 192 + n);
    o[(size_t)orow * 512 + h * 64 + lane] = acc[jj];
  }
}

// ================= kv-cache fill (fp32, per-head key rmsnorm) ==============
__global__ __launch_bounds__(128) void cache_fill_kernel(
    const float* __restrict__ kvp, const float* __restrict__ knw,
    float* __restrict__ Kc, float* __restrict__ Vc, int base_e)
{
  int n = blockIdx.x;
  int t = blockIdx.y;
  int g = t >> 1, b = t & 1;
  int e = base_e + g;
  int lane = threadIdx.x;  // 128 lanes x 4 cols; 16 lanes per head
  const float* src = kvp + ((size_t)t * 192 + n) * 1024;
  float k4[4];
  float ss = 0.f;
#pragma unroll
  for (int u = 0; u < 4; ++u) { k4[u] = src[lane * 4 + u]; ss += k4[u] * k4[u]; }
  for (int off = 8; off; off >>= 1) ss += __shfl_xor(ss, off, 16);
  float rs = rsqrtf(ss * (1.f / 64.f) + EPSV);
  float* kd = Kc + (((size_t)e * 2 + b) * 192 + n) * 512;
  float* vd = Vc + (((size_t)e * 2 + b) * 192 + n) * 512;
#pragma unroll
  for (int u = 0; u < 4; ++u) {
    int c = lane * 4 + u;
    kd[c] = k4[u] * rs * knw[c & 63];
    vd[c] = src[512 + c];
  }
}

// ===========================================================================
extern "C" void kernel_launch(void* const* d_in, const int* in_sizes, int n_in,
                              void* d_out, int out_size, void* d_ws, size_t ws_size,
                              hipStream_t stream)
{
  const float* tokens   = (const float*)d_in[0];
  const float* attn_nw  = (const float*)d_in[1];
  const float* attn_qw  = (const float*)d_in[2];
  const float* attn_kvw = (const float*)d_in[3];
  const float* attn_ow  = (const float*)d_in[4];
  const float* ff_nw    = (const float*)d_in[5];
  const float* ff_kw    = (const float*)d_in[6];
  const float* ff_kb    = (const float*)d_in[7];
  const float* ff_vw    = (const float*)d_in[8];
  const float* ff_vb    = (const float*)d_in[9];
  const float* res_nw   = (const float*)d_in[10];
  const float* res_knw  = (const float*)d_in[11];
  const float* res_qw   = (const float*)d_in[12];
  const float* res_kvw  = (const float*)d_in[13];
  const float* res_ow   = (const float*)d_in[14];
  const float* q_ro     = (const float*)d_in[15];
  const float* ro_nw    = (const float*)d_in[16];
  const float* ro_w     = (const float*)d_in[17];
  float* out = (float*)d_out;

  // ---- workspace carve-up (54,281,728 floats = 217.1 MB) ----
  float* ws = (float*)d_ws;
  const size_t NEED = 54281728ull * 4ull;
  if (ws_size < NEED) return;
  float* ffk_w   = ws;  ws += 6ull * 2816 * 512;   // 8,650,752 (perm+pad fp32)
  float* ffk_b   = ws;  ws += 6ull * 2816;         // 16,896
  float* ffv_w   = ws;  ws += 6ull * 512 * 1408;   // 4,325,376 (K-pad fp32)
  float* toks    = ws;  ws += 1179648;             // [6,2,192,512]
  float* hbuf    = ws;  ws += 2359296;             // [<=4608,512]
  float* msgbuf  = ws;  ws += 2359296;             // [2,6,2,192,512]
  float* scratch = ws;  ws += 4718592;             // union region
  float* rqn     = ws;  ws += 512;
  float* rq      = ws;  ws += 512;
  float* Kc      = ws;  ws += 15335424;            // [78,2,192,512]
  float* Vc      = ws;  ws += 15335424;
  // scratch union (all uses strictly serialized on `stream`):
  float* qbuf   = scratch;                 // [2304,512]
  float* kvbuf  = scratch + 1179648;       // [12,192,1024]
  float* obuf   = scratch + 3538944;       // [2304,512]
  float* kvpool = scratch;                 // [<=24,192,1024] = 4,718,592
  float* act    = scratch;                 // [2304,1408] = 3,244,032
  // readout aliases (msgbuf dead by then):
  float* robuf  = msgbuf;                  // [384,512]
  float* robuf2 = msgbuf + 196608;         // [384,512]
  float* ronorm = msgbuf + 393216;         // [384,512]

  auto gemm = [&](const float* A, const float* W, const float* bias, float* C,
                  int M, int N, int K, int ldc,
                  long long aStr, long long wStr, long long bStr, long long cStr,
                  int nb, int mode) {
    dim3 g((N + BN - 1) / BN, (M + BM - 1) / BM, nb);
    hipLaunchKernelGGL(gemm_f32split_kernel, g, dim3(256), 0, stream,
                       A, W, bias, C, M, N, K, ldc, aStr, wStr, bStr, cStr, mode);
  };

  // ---- FF weight prep (perm+pad) ----
  hipLaunchKernelGGL(ffk_perm_kernel, dim3((unsigned)((6ull * 2816 * 512 + 255) / 256)),
                     dim3(256), 0, stream, ff_kw, ff_kb, ffk_w, ffk_b);
  hipLaunchKernelGGL(ffv_pad_kernel, dim3((unsigned)((6ull * 512 * 1408 + 255) / 256)),
                     dim3(256), 0, stream, ff_vw, ffv_w);

  // ---- init: toks = broadcast(tokens); cache msg0 kv entries 0..5 ----
  {
    const int total = 6 * 2 * 192 * 512;
    hipLaunchKernelGGL(bcast_kernel, dim3((total + 255) / 256), dim3(256), 0, stream,
                       tokens, toks);
  }
  hipLaunchKernelGGL(rmsnorm_kernel, dim3(2304), dim3(256), 0, stream,
                     toks, res_nw, hbuf, 2304);
  gemm(hbuf, res_kvw, nullptr, kvpool, 384, 1024, 512, 1024,
       196608, 0, 0, 393216, 6, 0);
  hipLaunchKernelGGL(cache_fill_kernel, dim3(192, 12), dim3(128), 0, stream,
                     kvpool, res_knw, Kc, Vc, 0);

  for (int it = 0; it < 6; ++it) {
    // ---- block self-attention -> msgbuf[0] ----
    hipLaunchKernelGGL(rmsnorm_kernel, dim3(2304), dim3(256), 0, stream,
                       toks, attn_nw, hbuf, 384);
    gemm(hbuf, attn_qw, nullptr, qbuf, 384, 512, 512, 512,
         196608, 262144, 0, 196608, 6, 0);
    gemm(hbuf, attn_kvw, nullptr, kvbuf, 384, 1024, 512, 1024,
         196608, 524288, 0, 393216, 6, 0);
    hipLaunchKernelGGL(block_attn_kernel, dim3(48, 8, 12), dim3(256), 0, stream,
                       qbuf, kvbuf, obuf);
    gemm(obuf, attn_ow, nullptr, msgbuf, 384, 512, 512, 512,
         196608, 262144, 0, 196608, 6, 0);
    // ---- GEGLU FF (fused) -> msgbuf[1] ----
    hipLaunchKernelGGL(rmsnorm_kernel, dim3(2304), dim3(256), 0, stream,
                       toks, ff_nw, hbuf, 384);
    gemm(hbuf, ffk_w, ffk_b, act, 384, 2730, 512, 1408,
         196608, 1441792, 2816, 540672, 6, 1);       // clobbers qbuf/kvbuf (dead)
    gemm(act, ffv_w, ff_vb, msgbuf + 1179648, 384, 512, 1408, 512,
         540672, 720896, 512, 196608, 6, 0);
    // ---- cache kv for the two new messages ----
    hipLaunchKernelGGL(rmsnorm_kernel, dim3(4608), dim3(256), 0, stream,
                       msgbuf, res_nw, hbuf, 4608);
    gemm(hbuf, res_kvw, nullptr, kvpool, 384, 1024, 512, 1024,
         196608, 0, 0, 393216, 12, 0);               // clobbers act (dead)
    hipLaunchKernelGGL(cache_fill_kernel, dim3(192, 24), dim3(128), 0, stream,
                       kvpool, res_knw, Kc, Vc, (2 * it + 1) * 6);
    if (it == 5) break;
    // ---- pooled cross-attention over all cached entries -> new toks ----
    hipLaunchKernelGGL(rmsnorm_kernel, dim3(2304), dim3(256), 0, stream,
                       toks, res_nw, hbuf, 2304);
    gemm(hbuf, res_qw, nullptr, qbuf, 2304, 512, 512, 512,
         0, 0, 0, 0, 1, 0);                          // clobbers kvpool (dead)
    hipLaunchKernelGGL(pooled_attn_kernel, dim3(192, 8, 2), dim3(64), 0, stream,
                       qbuf, Kc, Vc, obuf, (3 + 2 * it) * 6, 0);
    gemm(obuf, res_ow, nullptr, toks, 2304, 512, 512, 512,
         0, 0, 0, 0, 1, 0);
  }

  // ---- readout ----
  hipLaunchKernelGGL(rmsnorm_kernel, dim3(1), dim3(256), 0, stream,
                     q_ro, res_nw, rqn, 1);
  gemm(rqn, res_qw, nullptr, rq, 1, 512, 512, 512, 0, 0, 0, 0, 1, 0);
  hipLaunchKernelGGL(pooled_attn_kernel, dim3(192, 8, 2), dim3(64), 0, stream,
                     rq, Kc, Vc, robuf, 78, 1);
  gemm(robuf, res_ow, nullptr, robuf2, 384, 512, 512, 512, 0, 0, 0, 0, 1, 0);
  hipLaunchKernelGGL(rmsnorm_kernel, dim3(384), dim3(256), 0, stream,
                     robuf2, ro_nw, ronorm, 384);
  gemm(ronorm, ro_w, nullptr, out, 384, 32000, 512, 32000, 0, 0, 0, 0, 1, 0);
}

// Round 11
// 2156.919 us; speedup vs baseline: 2.2184x; 1.3295x over previous
//
#include <hip/hip_runtime.h>
#include <hip/hip_bf16.h>
#include <math.h>

// ---------------------------------------------------------------------------
// DepthlessTransformer forward. Round 11 = round 10 (proven, 2868us) + two
// independent, value-preserving changes:
//  (1) GEMM tile templated <128,4>/<64,2>; small dispatches (<=144 blocks at
//      128^2) route to 64^2 tiles -> 288-576 blocks, fills all 256 CUs.
//      K-loop order unchanged -> bitwise-identical accumulation.
//  (2) block_attn: after QK+softmax, V is staged into the (now-dead) K LDS
//      tile once per block; PV reads LDS (was: each of 4 waves re-streaming
//      all 192 V rows from L2 -> 4x redundant traffic, FETCH 39MB vs 9.4MB).
// GEMM numerics: split-at-staging hi/lo bf16, 3 MFMAs, fp32 accumulate
// (r10-proven absmax 0.015625).
// D=512 H=8 DH=64 DI=512 L=6 NEX=6 FFI=1365 V=32000 B=2 N=192
// ---------------------------------------------------------------------------

#define EPSV 1.1920929e-07f
typedef __hip_bfloat16 bf16;
typedef __attribute__((ext_vector_type(4))) float f32x4;
typedef __attribute__((ext_vector_type(8))) short bf16x8;

// RTN split of 8 fp32 (two f32x4) into hi/lo bf16x8. Proven r5-10 numerics.
__device__ inline void split8r(f32x4 x0, f32x4 x1, bf16x8& h8, bf16x8& l8) {
#pragma unroll
  for (int i = 0; i < 4; ++i) {
    bf16 h0 = __float2bfloat16(x0[i]);
    h8[i] = __builtin_bit_cast(short, h0);
    l8[i] = __builtin_bit_cast(short, __float2bfloat16(x0[i] - __bfloat162float(h0)));
    bf16 h1 = __float2bfloat16(x1[i]);
    h8[i + 4] = __builtin_bit_cast(short, h1);
    l8[i + 4] = __builtin_bit_cast(short, __float2bfloat16(x1[i] - __bfloat162float(h1)));
  }
}

// ============== split-at-staging GEMM: C = A * W^T (+bias), fp32 in/out ====
// Template: BMN = square tile dim (128 or 64); MR = fragments per wave dim.
// A: [M,K] fp32 (batch stride aStr); W: [Nt,K] fp32 (batch stride wStr),
// Nt rounded up to BMN rows readable. C: [M,ldc] fp32. K % 32 == 0.
// LDS: hi/lo bf16 tiles, row pitch 40 bf16 (80B, 16B-aligned) -> 2-way banks.
// mode 0: plain (+optional bias). mode 1: GEGLU fused -- W rows interleaved
// (2c=sim_c, 2c+1=gate_c), writes act[row][col>>1] = z_sim*gelu(z_gate).
#define BKG 32
#define LDB 40
template <int BMN, int MR>
__global__ __launch_bounds__(256) void gemm_split_t(
    const float* __restrict__ A, const float* __restrict__ W,
    const float* __restrict__ bias, float* __restrict__ C,
    int M, int N, int K, int ldc,
    long long aStr, long long wStr, long long bStr, long long cStr, int mode)
{
  int batch = blockIdx.z;
  A += (size_t)batch * aStr;
  W += (size_t)batch * wStr;
  C += (size_t)batch * cStr;
  if (bias) bias += (size_t)batch * bStr;
  int m0 = blockIdx.y * BMN, n0 = blockIdx.x * BMN;

  __shared__ short Ah[BMN * LDB], Al[BMN * LDB];
  __shared__ short Wh[BMN * LDB], Wl[BMN * LDB];

  int t = threadIdx.x;
  int wave = t >> 6, lane = t & 63;
  const int HALF = BMN / 2;
  int wr = wave >> 1, wc = wave & 1;       // wave's HALFxHALF quadrant
  int fr = lane & 15, fq = lane >> 4;      // fragment row + k-group
  int srow = t >> 2;                       // staging rows srow (+64)
  int scol = (t & 3) * 8;                  // float col 0,8,16,24

  f32x4 acc[MR][MR] = {};

  for (int k0 = 0; k0 < K; k0 += BKG) {
    // ---- stage: load fp32, split to bf16 hi/lo, ds_write both tiles ----
#pragma unroll
    for (int r0 = 0; r0 < BMN; r0 += 64) {
      int row = r0 + srow;
      const float* pa = A + (size_t)(m0 + row) * K + k0 + scol;
      const float* pw = W + (size_t)(n0 + row) * K + k0 + scol;
      f32x4 a0 = *(const f32x4*)pa, a1 = *(const f32x4*)(pa + 4);
      f32x4 w0 = *(const f32x4*)pw, w1 = *(const f32x4*)(pw + 4);
      bf16x8 h, l;
      split8r(a0, a1, h, l);
      *(bf16x8*)&Ah[row * LDB + scol] = h;
      *(bf16x8*)&Al[row * LDB + scol] = l;
      split8r(w0, w1, h, l);
      *(bf16x8*)&Wh[row * LDB + scol] = h;
      *(bf16x8*)&Wl[row * LDB + scol] = l;
    }
    __syncthreads();
    bf16x8 ah[MR], al[MR], wh[MR], wl[MR];
#pragma unroll
    for (int m = 0; m < MR; ++m) {
      int r = (wr * HALF + m * 16 + fr) * LDB + fq * 8;
      ah[m] = *(const bf16x8*)&Ah[r];
      al[m] = *(const bf16x8*)&Al[r];
    }
#pragma unroll
    for (int n = 0; n < MR; ++n) {
      int r = (wc * HALF + n * 16 + fr) * LDB + fq * 8;
      wh[n] = *(const bf16x8*)&Wh[r];
      wl[n] = *(const bf16x8*)&Wl[r];
    }
#pragma unroll
    for (int m = 0; m < MR; ++m)
#pragma unroll
      for (int n = 0; n < MR; ++n) {
        acc[m][n] = __builtin_amdgcn_mfma_f32_16x16x32_bf16(ah[m], wh[n], acc[m][n], 0, 0, 0);
        acc[m][n] = __builtin_amdgcn_mfma_f32_16x16x32_bf16(al[m], wh[n], acc[m][n], 0, 0, 0);
        acc[m][n] = __builtin_amdgcn_mfma_f32_16x16x32_bf16(ah[m], wl[n], acc[m][n], 0, 0, 0);
      }
    __syncthreads();
  }

  if (mode == 0) {
#pragma unroll
    for (int m = 0; m < MR; ++m)
#pragma unroll
      for (int n = 0; n < MR; ++n) {
        int col = n0 + wc * HALF + n * 16 + fr;
        if (col >= N) continue;
        float bv = bias ? bias[col] : 0.f;
#pragma unroll
        for (int j = 0; j < 4; ++j) {
          int row = m0 + wr * HALF + m * 16 + fq * 4 + j;
          if (row < M) C[(size_t)row * ldc + col] = acc[m][n][j] + bv;
        }
      }
  } else {
    // GEGLU: even col = sim, odd col = gate (interleaved weight rows).
#pragma unroll
    for (int m = 0; m < MR; ++m)
#pragma unroll
      for (int n = 0; n < MR; ++n) {
        int col = n0 + wc * HALF + n * 16 + fr;
        float bv = bias[col];
#pragma unroll
        for (int j = 0; j < 4; ++j) {
          float z = acc[m][n][j] + bv;
          float zn = __shfl_xor(z, 1);   // partner: sim<->gate
          if (!(col & 1) && col < N) {
            float g = zn;
            float a = z * (0.5f * g * (1.f + erff(g * 0.70710678118654752f)));
            int row = m0 + wr * HALF + m * 16 + fq * 4 + j;
            if (row < M) C[(size_t)row * ldc + (col >> 1)] = a;
          }
        }
      }
  }
}

// ====== FF-keys weight perm+pad: [6,2730,512] -> [6,2816,512] interleaved ==
__global__ void ffk_perm_kernel(const float* __restrict__ kw,
                                const float* __restrict__ kb,
                                float* __restrict__ wout, float* __restrict__ bout)
{
  size_t idx = (size_t)blockIdx.x * 256 + threadIdx.x;
  const size_t per = 2816ull * 512;
  if (idx < 6 * per) {
    int b = (int)(idx / per);
    size_t r2 = idx % per;
    int r = (int)(r2 >> 9), k = (int)(r2 & 511);
    float v = 0.f;
    if (r < 2730) {
      int c = (r >> 1) + (r & 1) * 1365;
      v = kw[((size_t)b * 2730 + c) * 512 + k];
    }
    wout[idx] = v;
  }
  if (idx < 6 * 2816) {
    int b = (int)(idx / 2816), r = (int)(idx % 2816);
    float v = 0.f;
    if (r < 2730) {
      int c = (r >> 1) + (r & 1) * 1365;
      v = kb[(size_t)b * 2730 + c];
    }
    bout[idx] = v;
  }
}

// ====== FF-vals weight pad: [6,512,1365] -> [6,512,1408] (K zero-pad) ======
__global__ void ffv_pad_kernel(const float* __restrict__ vw, float* __restrict__ wout)
{
  size_t idx = (size_t)blockIdx.x * 256 + threadIdx.x;
  const size_t total = 6ull * 512 * 1408;
  if (idx >= total) return;
  int k = (int)(idx % 1408);
  size_t nr = idx / 1408;   // b*512 + n
  wout[idx] = (k < 1365) ? vw[nr * 1365 + k] : 0.f;
}

// ================= rmsnorm over dim 512 (fp32 -> fp32) =====================
__global__ __launch_bounds__(256) void rmsnorm_kernel(
    const float* __restrict__ x, const float* __restrict__ w,
    float* __restrict__ out, int rows_per_w)
{
  int r = blockIdx.x;
  int t = threadIdx.x;
  const float* xr = x + (size_t)r * 512;
  float a = xr[t], b = xr[t + 256];
  float ss = a * a + b * b;
  for (int off = 32; off; off >>= 1) ss += __shfl_xor(ss, off);
  __shared__ float wsum[4];
  if ((t & 63) == 0) wsum[t >> 6] = ss;
  __syncthreads();
  float tot = wsum[0] + wsum[1] + wsum[2] + wsum[3];
  float rs = rsqrtf(tot * (1.f / 512.f) + EPSV);
  const float* wr = w + (size_t)(r / rows_per_w) * 512;
  out[(size_t)r * 512 + t] = a * rs * wr[t];
  out[(size_t)r * 512 + t + 256] = b * rs * wr[t + 256];
}

// ================= broadcast tokens -> toks[L] =============================
__global__ void bcast_kernel(const float* __restrict__ tokens, float* __restrict__ toks)
{
  size_t idx = (size_t)blockIdx.x * 256 + threadIdx.x;
  const size_t total = (size_t)6 * 2 * 192 * 512;
  if (idx >= total) return;
  toks[idx] = tokens[idx % ((size_t)2 * 192 * 512)];
}

// ================= block self-attention, LDS-staged K then V ===============
// grid (48, 8, 12), 256 threads = 4 waves; wave w handles query i = bx*4+w.
// Phase 1: K staged in LDS, QK scores + softmax -> ps (per-wave).
// Phase 2: V staged into the SAME LDS tile (K dead), PV from LDS.
__global__ __launch_bounds__(256) void block_attn_kernel(
    const float* __restrict__ q, const float* __restrict__ kv, float* __restrict__ o)
{
  int h = blockIdx.y, lb = blockIdx.z;
  int t = threadIdx.x;
  int wave = t >> 6, lane = t & 63;
  int i = blockIdx.x * 4 + wave;

  __shared__ float Ks[192][65];   // 49,920 B (K, then reused for V)
  __shared__ float qs[4][64];
  __shared__ float ps[4][192];

  const float* kb = kv + (size_t)lb * 192 * 1024 + h * 64;
#pragma unroll
  for (int c = 0; c < 48; ++c) {
    int idx = c * 256 + t;
    int row = idx >> 6, col = idx & 63;
    Ks[row][col] = kb[(size_t)row * 1024 + col];
  }
  const float* qrow = q + ((size_t)(lb * 192 + i)) * 512 + h * 64;
  qs[wave][lane] = qrow[lane];
  __syncthreads();

  float s[3];
#pragma unroll
  for (int r = 0; r < 3; ++r) {
    int j = lane + r * 64;
    float acc = 0.f;
#pragma unroll 8
    for (int d = 0; d < 64; ++d) acc += qs[wave][d] * Ks[j][d];
    s[r] = acc;
  }
  float mx = fmaxf(fmaxf(s[0], s[1]), s[2]);
  for (int off = 32; off; off >>= 1) mx = fmaxf(mx, __shfl_xor(mx, off));
  float sum = 0.f;
#pragma unroll
  for (int r = 0; r < 3; ++r) { s[r] = expf(s[r] - mx); sum += s[r]; }
  for (int off = 32; off; off >>= 1) sum += __shfl_xor(sum, off);
  float inv = 1.f / sum;
#pragma unroll
  for (int r = 0; r < 3; ++r) ps[wave][lane + r * 64] = s[r] * inv;

  // ---- phase 2: stage V over K (all waves done with Ks), PV from LDS ----
  __syncthreads();
  const float* vb = kb + 512;
#pragma unroll
  for (int c = 0; c < 48; ++c) {
    int idx = c * 256 + t;
    int row = idx >> 6, col = idx & 63;
    Ks[row][col] = vb[(size_t)row * 1024 + col];
  }
  __syncthreads();
  float acc = 0.f;
  for (int j = 0; j < 192; ++j) acc += ps[wave][j] * Ks[j][lane];
  o[((size_t)(lb * 192 + i)) * 512 + h * 64 + lane] = acc;
}

// ================= pooled attention, K/V amortized over 6 queries ==========
__global__ __launch_bounds__(64) void pooled_attn_kernel(
    const float* __restrict__ q, const float* __restrict__ Kc,
    const float* __restrict__ Vc, float* __restrict__ o, int M, int mode)
{
  int n = blockIdx.x, h = blockIdx.y, z = blockIdx.z;
  int lane = threadIdx.x;
  int nq = mode ? 1 : 6;

  __shared__ float Ks[80][65];    // 20,800 B
  __shared__ float qs[6][64];
  __shared__ float p[6][128];

  for (int m = 0; m < M; ++m)
    Ks[m][lane] = Kc[(((size_t)m * 2 + z) * 192 + n) * 512 + h * 64 + lane];
  for (int jj = 0; jj < nq; ++jj) {
    const float* qrow = mode ? (q + h * 64)
                             : (q + ((size_t)((z * 6 + jj) * 192 + n)) * 512 + h * 64);
    qs[jj][lane] = qrow[lane];
  }
  __syncthreads();

  float d0[6] = {}, d1[6] = {};
  int m1 = lane + 64;
#pragma unroll 4
  for (int d = 0; d < 64; ++d) {
    float k0 = Ks[lane][d];
    float k1 = Ks[m1 & 79][d];
#pragma unroll
    for (int jj = 0; jj < 6; ++jj) {
      float qv = qs[jj][d];
      d0[jj] += qv * k0;
      d1[jj] += qv * k1;
    }
  }
  float acc[6] = {};
#pragma unroll
  for (int jj = 0; jj < 6; ++jj) {
    if (jj >= nq) break;
    float s0 = (lane < M) ? d0[jj] : -1e30f;
    float s1 = (m1 < M) ? d1[jj] : -1e30f;
    float mx = fmaxf(s0, s1);
    for (int off = 32; off; off >>= 1) mx = fmaxf(mx, __shfl_xor(mx, off));
    float e0 = (lane < M) ? expf(s0 - mx) : 0.f;
    float e1 = (m1 < M) ? expf(s1 - mx) : 0.f;
    float sum = e0 + e1;
    for (int off = 32; off; off >>= 1) sum += __shfl_xor(sum, off);
    float inv = 1.f / sum;
    p[jj][lane] = e0 * inv;
    p[jj][m1] = e1 * inv;
  }
  __syncthreads();

  for (int m = 0; m < M; ++m) {
    float v = Vc[(((size_t)m * 2 + z) * 192 + n) * 512 + h * 64 + lane];
#pragma unroll
    for (int jj = 0; jj < 6; ++jj) acc[jj] += p[jj][m] * v;
  }
#pragma unroll
  for (int jj = 0; jj < 6; ++jj) {
    if (jj >= nq) break;
    int orow = mode ? (z * 192 + n) : ((z * 6 + jj) * 192 + n);
    o[(size_t)orow * 512 + h * 64 + lane] = acc[jj];
  }
}

// ================= kv-cache fill (fp32, per-head key rmsnorm) ==============
__global__ __launch_bounds__(128) void cache_fill_kernel(
    const float* __restrict__ kvp, const float* __restrict__ knw,
    float* __restrict__ Kc, float* __restrict__ Vc, int base_e)
{
  int n = blockIdx.x;
  int t = blockIdx.y;
  int g = t >> 1, b = t & 1;
  int e = base_e + g;
  int lane = threadIdx.x;  // 128 lanes x 4 cols; 16 lanes per head
  const float* src = kvp + ((size_t)t * 192 + n) * 1024;
  float k4[4];
  float ss = 0.f;
#pragma unroll
  for (int u = 0; u < 4; ++u) { k4[u] = src[lane * 4 + u]; ss += k4[u] * k4[u]; }
  for (int off = 8; off; off >>= 1) ss += __shfl_xor(ss, off, 16);
  float rs = rsqrtf(ss * (1.f / 64.f) + EPSV);
  float* kd = Kc + (((size_t)e * 2 + b) * 192 + n) * 512;
  float* vd = Vc + (((size_t)e * 2 + b) * 192 + n) * 512;
#pragma unroll
  for (int u = 0; u < 4; ++u) {
    int c = lane * 4 + u;
    kd[c] = k4[u] * rs * knw[c & 63];
    vd[c] = src[512 + c];
  }
}

// ===========================================================================
extern "C" void kernel_launch(void* const* d_in, const int* in_sizes, int n_in,
                              void* d_out, int out_size, void* d_ws, size_t ws_size,
                              hipStream_t stream)
{
  const float* tokens   = (const float*)d_in[0];
  const float* attn_nw  = (const float*)d_in[1];
  const float* attn_qw  = (const float*)d_in[2];
  const float* attn_kvw = (const float*)d_in[3];
  const float* attn_ow  = (const float*)d_in[4];
  const float* ff_nw    = (const float*)d_in[5];
  const float* ff_kw    = (const float*)d_in[6];
  const float* ff_kb    = (const float*)d_in[7];
  const float* ff_vw    = (const float*)d_in[8];
  const float* ff_vb    = (const float*)d_in[9];
  const float* res_nw   = (const float*)d_in[10];
  const float* res_knw  = (const float*)d_in[11];
  const float* res_qw   = (const float*)d_in[12];
  const float* res_kvw  = (const float*)d_in[13];
  const float* res_ow   = (const float*)d_in[14];
  const float* q_ro     = (const float*)d_in[15];
  const float* ro_nw    = (const float*)d_in[16];
  const float* ro_w     = (const float*)d_in[17];
  float* out = (float*)d_out;

  // ---- workspace carve-up (54,281,728 floats = 217.1 MB) ----
  float* ws = (float*)d_ws;
  const size_t NEED = 54281728ull * 4ull;
  if (ws_size < NEED) return;
  float* ffk_w   = ws;  ws += 6ull * 2816 * 512;   // 8,650,752 (perm+pad fp32)
  float* ffk_b   = ws;  ws += 6ull * 2816;         // 16,896
  float* ffv_w   = ws;  ws += 6ull * 512 * 1408;   // 4,325,376 (K-pad fp32)
  float* toks    = ws;  ws += 1179648;             // [6,2,192,512]
  float* hbuf    = ws;  ws += 2359296;             // [<=4608,512]
  float* msgbuf  = ws;  ws += 2359296;             // [2,6,2,192,512]
  float* scratch = ws;  ws += 4718592;             // union region
  float* rqn     = ws;  ws += 512;
  float* rq      = ws;  ws += 512;
  float* Kc      = ws;  ws += 15335424;            // [78,2,192,512]
  float* Vc      = ws;  ws += 15335424;
  // scratch union (all uses strictly serialized on `stream`):
  float* qbuf   = scratch;                 // [2304,512]
  float* kvbuf  = scratch + 1179648;       // [12,192,1024]
  float* obuf   = scratch + 3538944;       // [2304,512]
  float* kvpool = scratch;                 // [<=24,192,1024] = 4,718,592
  float* act    = scratch;                 // [2304,1408] = 3,244,032
  // readout aliases (msgbuf dead by then):
  float* robuf  = msgbuf;                  // [384,512]
  float* robuf2 = msgbuf + 196608;         // [384,512]
  float* ronorm = msgbuf + 393216;         // [384,512]

  auto gemm = [&](const float* A, const float* W, const float* bias, float* C,
                  int M, int N, int K, int ldc,
                  long long aStr, long long wStr, long long bStr, long long cStr,
                  int nb, int mode) {
    int gx = (N + 127) / 128, gy = (M + 127) / 128;
    if (mode == 0 && gx * gy * nb <= 144) {
      dim3 g((N + 63) / 64, (M + 63) / 64, nb);
      hipLaunchKernelGGL((gemm_split_t<64, 2>), g, dim3(256), 0, stream,
                         A, W, bias, C, M, N, K, ldc, aStr, wStr, bStr, cStr, mode);
    } else {
      dim3 g(gx, gy, nb);
      hipLaunchKernelGGL((gemm_split_t<128, 4>), g, dim3(256), 0, stream,
                         A, W, bias, C, M, N, K, ldc, aStr, wStr, bStr, cStr, mode);
    }
  };

  // ---- FF weight prep (perm+pad) ----
  hipLaunchKernelGGL(ffk_perm_kernel, dim3((unsigned)((6ull * 2816 * 512 + 255) / 256)),
                     dim3(256), 0, stream, ff_kw, ff_kb, ffk_w, ffk_b);
  hipLaunchKernelGGL(ffv_pad_kernel, dim3((unsigned)((6ull * 512 * 1408 + 255) / 256)),
                     dim3(256), 0, stream, ff_vw, ffv_w);

  // ---- init: toks = broadcast(tokens); cache msg0 kv entries 0..5 ----
  {
    const int total = 6 * 2 * 192 * 512;
    hipLaunchKernelGGL(bcast_kernel, dim3((total + 255) / 256), dim3(256), 0, stream,
                       tokens, toks);
  }
  hipLaunchKernelGGL(rmsnorm_kernel, dim3(2304), dim3(256), 0, stream,
                     toks, res_nw, hbuf, 2304);
  gemm(hbuf, res_kvw, nullptr, kvpool, 384, 1024, 512, 1024,
       196608, 0, 0, 393216, 6, 0);
  hipLaunchKernelGGL(cache_fill_kernel, dim3(192, 12), dim3(128), 0, stream,
                     kvpool, res_knw, Kc, Vc, 0);

  for (int it = 0; it < 6; ++it) {
    // ---- block self-attention -> msgbuf[0] ----
    hipLaunchKernelGGL(rmsnorm_kernel, dim3(2304), dim3(256), 0, stream,
                       toks, attn_nw, hbuf, 384);
    gemm(hbuf, attn_qw, nullptr, qbuf, 384, 512, 512, 512,
         196608, 262144, 0, 196608, 6, 0);
    gemm(hbuf, attn_kvw, nullptr, kvbuf, 384, 1024, 512, 1024,
         196608, 524288, 0, 393216, 6, 0);
    hipLaunchKernelGGL(block_attn_kernel, dim3(48, 8, 12), dim3(256), 0, stream,
                       qbuf, kvbuf, obuf);
    gemm(obuf, attn_ow, nullptr, msgbuf, 384, 512, 512, 512,
         196608, 262144, 0, 196608, 6, 0);
    // ---- GEGLU FF (fused) -> msgbuf[1] ----
    hipLaunchKernelGGL(rmsnorm_kernel, dim3(2304), dim3(256), 0, stream,
                       toks, ff_nw, hbuf, 384);
    gemm(hbuf, ffk_w, ffk_b, act, 384, 2730, 512, 1408,
         196608, 1441792, 2816, 540672, 6, 1);       // clobbers qbuf/kvbuf (dead)
    gemm(act, ffv_w, ff_vb, msgbuf + 1179648, 384, 512, 1408, 512,
         540672, 720896, 512, 196608, 6, 0);
    // ---- cache kv for the two new messages ----
    hipLaunchKernelGGL(rmsnorm_kernel, dim3(4608), dim3(256), 0, stream,
                       msgbuf, res_nw, hbuf, 4608);
    gemm(hbuf, res_kvw, nullptr, kvpool, 384, 1024, 512, 1024,
         196608, 0, 0, 393216, 12, 0);               // clobbers act (dead)
    hipLaunchKernelGGL(cache_fill_kernel, dim3(192, 24), dim3(128), 0, stream,
                       kvpool, res_knw, Kc, Vc, (2 * it + 1) * 6);
    if (it == 5) break;
    // ---- pooled cross-attention over all cached entries -> new toks ----
    hipLaunchKernelGGL(rmsnorm_kernel, dim3(2304), dim3(256), 0, stream,
                       toks, res_nw, hbuf, 2304);
    gemm(hbuf, res_qw, nullptr, qbuf, 2304, 512, 512, 512,
         0, 0, 0, 0, 1, 0);                          // clobbers kvpool (dead)
    hipLaunchKernelGGL(pooled_attn_kernel, dim3(192, 8, 2), dim3(64), 0, stream,
                       qbuf, Kc, Vc, obuf, (3 + 2 * it) * 6, 0);
    gemm(obuf, res_ow, nullptr, toks, 2304, 512, 512, 512,
         0, 0, 0, 0, 1, 0);
  }

  // ---- readout ----
  hipLaunchKernelGGL(rmsnorm_kernel, dim3(1), dim3(256), 0, stream,
                     q_ro, res_nw, rqn, 1);
  gemm(rqn, res_qw, nullptr, rq, 1, 512, 512, 512, 0, 0, 0, 0, 1, 0);
  hipLaunchKernelGGL(pooled_attn_kernel, dim3(192, 8, 2), dim3(64), 0, stream,
                     rq, Kc, Vc, robuf, 78, 1);
  gemm(robuf, res_ow, nullptr, robuf2, 384, 512, 512, 512, 0, 0, 0, 0, 1, 0);
  hipLaunchKernelGGL(rmsnorm_kernel, dim3(384), dim3(256), 0, stream,
                     robuf2, ro_nw, ronorm, 384);
  gemm(ronorm, ro_w, nullptr, out, 384, 32000, 512, 32000, 0, 0, 0, 0, 1, 0);
}

// Round 12
// 2003.961 us; speedup vs baseline: 2.3878x; 1.0763x over previous
//
#include <hip/hip_runtime.h>
#include <hip/hip_bf16.h>
#include <math.h>

// ---------------------------------------------------------------------------
// DepthlessTransformer forward. Round 12 = round 11 (proven, 2157us) + ONE
// structural change: the GEMM K-loop register-prefetches step k+1's global
// loads while step k computes (split+ds_write current -> issue next loads ->
// barrier -> ds_read+MFMA -> barrier). r11 counters showed the GEMMs
// latency-bound (MfmaUtil 18%, VALU 23%, HBM 24%, nothing saturated): the
// serial load->split->write chain exposed ~500cy global latency on each of
// 16 K-steps. Same addresses, same LDS layout, same accumulation order ->
// bitwise-identical output (absmax 0.015625).
// D=512 H=8 DH=64 DI=512 L=6 NEX=6 FFI=1365 V=32000 B=2 N=192
// ---------------------------------------------------------------------------

#define EPSV 1.1920929e-07f
typedef __hip_bfloat16 bf16;
typedef __attribute__((ext_vector_type(4))) float f32x4;
typedef __attribute__((ext_vector_type(8))) short bf16x8;

// RTN split of 8 fp32 (two f32x4) into hi/lo bf16x8. Proven r5-11 numerics.
__device__ inline void split8r(f32x4 x0, f32x4 x1, bf16x8& h8, bf16x8& l8) {
#pragma unroll
  for (int i = 0; i < 4; ++i) {
    bf16 h0 = __float2bfloat16(x0[i]);
    h8[i] = __builtin_bit_cast(short, h0);
    l8[i] = __builtin_bit_cast(short, __float2bfloat16(x0[i] - __bfloat162float(h0)));
    bf16 h1 = __float2bfloat16(x1[i]);
    h8[i + 4] = __builtin_bit_cast(short, h1);
    l8[i + 4] = __builtin_bit_cast(short, __float2bfloat16(x1[i] - __bfloat162float(h1)));
  }
}

// ============== split-at-staging GEMM: C = A * W^T (+bias), fp32 in/out ====
// Template: BMN = square tile dim (128 or 64); MR = fragments per wave dim.
// A: [M,K] fp32 (batch stride aStr); W: [Nt,K] fp32 (batch stride wStr),
// Nt rounded up to BMN rows readable. C: [M,ldc] fp32. K % 32 == 0.
// LDS: hi/lo bf16 tiles, row pitch 40 bf16 (80B, 16B-aligned) -> 2-way banks.
// K-loop register-prefetches the next step's A/W (16 VGPRs) so global
// latency hides under the current step's barrier+ds_read+MFMA.
// mode 0: plain (+optional bias). mode 1: GEGLU fused -- W rows interleaved
// (2c=sim_c, 2c+1=gate_c), writes act[row][col>>1] = z_sim*gelu(z_gate).
#define BKG 32
#define LDB 40
template <int BMN, int MR>
__global__ __launch_bounds__(256) void gemm_split_t(
    const float* __restrict__ A, const float* __restrict__ W,
    const float* __restrict__ bias, float* __restrict__ C,
    int M, int N, int K, int ldc,
    long long aStr, long long wStr, long long bStr, long long cStr, int mode)
{
  int batch = blockIdx.z;
  A += (size_t)batch * aStr;
  W += (size_t)batch * wStr;
  C += (size_t)batch * cStr;
  if (bias) bias += (size_t)batch * bStr;
  int m0 = blockIdx.y * BMN, n0 = blockIdx.x * BMN;

  __shared__ short Ah[BMN * LDB], Al[BMN * LDB];
  __shared__ short Wh[BMN * LDB], Wl[BMN * LDB];

  int t = threadIdx.x;
  int wave = t >> 6, lane = t & 63;
  const int HALF = BMN / 2;
  const int NR = BMN / 64;                 // staged 64-row groups
  int wr = wave >> 1, wc = wave & 1;       // wave's HALFxHALF quadrant
  int fr = lane & 15, fq = lane >> 4;      // fragment row + k-group
  int srow = t >> 2;                       // staging rows r0+srow
  int scol = (t & 3) * 8;                  // float col 0,8,16,24

  f32x4 acc[MR][MR] = {};
  f32x4 pa0[NR], pa1[NR], pw0[NR], pw1[NR];

  // prologue: load K-step 0 into registers
#pragma unroll
  for (int r = 0; r < NR; ++r) {
    int row = r * 64 + srow;
    const float* pa = A + (size_t)(m0 + row) * K + scol;
    const float* pw = W + (size_t)(n0 + row) * K + scol;
    pa0[r] = *(const f32x4*)pa;  pa1[r] = *(const f32x4*)(pa + 4);
    pw0[r] = *(const f32x4*)pw;  pw1[r] = *(const f32x4*)(pw + 4);
  }

  for (int k0 = 0; k0 < K; k0 += BKG) {
    // ---- split + ds_write the CURRENT step from registers ----
#pragma unroll
    for (int r = 0; r < NR; ++r) {
      int row = r * 64 + srow;
      bf16x8 h, l;
      split8r(pa0[r], pa1[r], h, l);
      *(bf16x8*)&Ah[row * LDB + scol] = h;
      *(bf16x8*)&Al[row * LDB + scol] = l;
      split8r(pw0[r], pw1[r], h, l);
      *(bf16x8*)&Wh[row * LDB + scol] = h;
      *(bf16x8*)&Wl[row * LDB + scol] = l;
    }
    // ---- issue NEXT step's global loads (consumed after next barrier) ----
    if (k0 + BKG < K) {
      int kn = k0 + BKG;
#pragma unroll
      for (int r = 0; r < NR; ++r) {
        int row = r * 64 + srow;
        const float* pa = A + (size_t)(m0 + row) * K + kn + scol;
        const float* pw = W + (size_t)(n0 + row) * K + kn + scol;
        pa0[r] = *(const f32x4*)pa;  pa1[r] = *(const f32x4*)(pa + 4);
        pw0[r] = *(const f32x4*)pw;  pw1[r] = *(const f32x4*)(pw + 4);
      }
    }
    __syncthreads();
    bf16x8 ah[MR], al[MR], wh[MR], wl[MR];
#pragma unroll
    for (int m = 0; m < MR; ++m) {
      int r = (wr * HALF + m * 16 + fr) * LDB + fq * 8;
      ah[m] = *(const bf16x8*)&Ah[r];
      al[m] = *(const bf16x8*)&Al[r];
    }
#pragma unroll
    for (int n = 0; n < MR; ++n) {
      int r = (wc * HALF + n * 16 + fr) * LDB + fq * 8;
      wh[n] = *(const bf16x8*)&Wh[r];
      wl[n] = *(const bf16x8*)&Wl[r];
    }
#pragma unroll
    for (int m = 0; m < MR; ++m)
#pragma unroll
      for (int n = 0; n < MR; ++n) {
        acc[m][n] = __builtin_amdgcn_mfma_f32_16x16x32_bf16(ah[m], wh[n], acc[m][n], 0, 0, 0);
        acc[m][n] = __builtin_amdgcn_mfma_f32_16x16x32_bf16(al[m], wh[n], acc[m][n], 0, 0, 0);
        acc[m][n] = __builtin_amdgcn_mfma_f32_16x16x32_bf16(ah[m], wl[n], acc[m][n], 0, 0, 0);
      }
    __syncthreads();
  }

  if (mode == 0) {
#pragma unroll
    for (int m = 0; m < MR; ++m)
#pragma unroll
      for (int n = 0; n < MR; ++n) {
        int col = n0 + wc * HALF + n * 16 + fr;
        if (col >= N) continue;
        float bv = bias ? bias[col] : 0.f;
#pragma unroll
        for (int j = 0; j < 4; ++j) {
          int row = m0 + wr * HALF + m * 16 + fq * 4 + j;
          if (row < M) C[(size_t)row * ldc + col] = acc[m][n][j] + bv;
        }
      }
  } else {
    // GEGLU: even col = sim, odd col = gate (interleaved weight rows).
#pragma unroll
    for (int m = 0; m < MR; ++m)
#pragma unroll
      for (int n = 0; n < MR; ++n) {
        int col = n0 + wc * HALF + n * 16 + fr;
        float bv = bias[col];
#pragma unroll
        for (int j = 0; j < 4; ++j) {
          float z = acc[m][n][j] + bv;
          float zn = __shfl_xor(z, 1);   // partner: sim<->gate
          if (!(col & 1) && col < N) {
            float g = zn;
            float a = z * (0.5f * g * (1.f + erff(g * 0.70710678118654752f)));
            int row = m0 + wr * HALF + m * 16 + fq * 4 + j;
            if (row < M) C[(size_t)row * ldc + (col >> 1)] = a;
          }
        }
      }
  }
}

// ====== FF-keys weight perm+pad: [6,2730,512] -> [6,2816,512] interleaved ==
__global__ void ffk_perm_kernel(const float* __restrict__ kw,
                                const float* __restrict__ kb,
                                float* __restrict__ wout, float* __restrict__ bout)
{
  size_t idx = (size_t)blockIdx.x * 256 + threadIdx.x;
  const size_t per = 2816ull * 512;
  if (idx < 6 * per) {
    int b = (int)(idx / per);
    size_t r2 = idx % per;
    int r = (int)(r2 >> 9), k = (int)(r2 & 511);
    float v = 0.f;
    if (r < 2730) {
      int c = (r >> 1) + (r & 1) * 1365;
      v = kw[((size_t)b * 2730 + c) * 512 + k];
    }
    wout[idx] = v;
  }
  if (idx < 6 * 2816) {
    int b = (int)(idx / 2816), r = (int)(idx % 2816);
    float v = 0.f;
    if (r < 2730) {
      int c = (r >> 1) + (r & 1) * 1365;
      v = kb[(size_t)b * 2730 + c];
    }
    bout[idx] = v;
  }
}

// ====== FF-vals weight pad: [6,512,1365] -> [6,512,1408] (K zero-pad) ======
__global__ void ffv_pad_kernel(const float* __restrict__ vw, float* __restrict__ wout)
{
  size_t idx = (size_t)blockIdx.x * 256 + threadIdx.x;
  const size_t total = 6ull * 512 * 1408;
  if (idx >= total) return;
  int k = (int)(idx % 1408);
  size_t nr = idx / 1408;   // b*512 + n
  wout[idx] = (k < 1365) ? vw[nr * 1365 + k] : 0.f;
}

// ================= rmsnorm over dim 512 (fp32 -> fp32) =====================
__global__ __launch_bounds__(256) void rmsnorm_kernel(
    const float* __restrict__ x, const float* __restrict__ w,
    float* __restrict__ out, int rows_per_w)
{
  int r = blockIdx.x;
  int t = threadIdx.x;
  const float* xr = x + (size_t)r * 512;
  float a = xr[t], b = xr[t + 256];
  float ss = a * a + b * b;
  for (int off = 32; off; off >>= 1) ss += __shfl_xor(ss, off);
  __shared__ float wsum[4];
  if ((t & 63) == 0) wsum[t >> 6] = ss;
  __syncthreads();
  float tot = wsum[0] + wsum[1] + wsum[2] + wsum[3];
  float rs = rsqrtf(tot * (1.f / 512.f) + EPSV);
  const float* wr = w + (size_t)(r / rows_per_w) * 512;
  out[(size_t)r * 512 + t] = a * rs * wr[t];
  out[(size_t)r * 512 + t + 256] = b * rs * wr[t + 256];
}

// ================= broadcast tokens -> toks[L] =============================
__global__ void bcast_kernel(const float* __restrict__ tokens, float* __restrict__ toks)
{
  size_t idx = (size_t)blockIdx.x * 256 + threadIdx.x;
  const size_t total = (size_t)6 * 2 * 192 * 512;
  if (idx >= total) return;
  toks[idx] = tokens[idx % ((size_t)2 * 192 * 512)];
}

// ================= block self-attention, LDS-staged K then V ===============
// grid (48, 8, 12), 256 threads = 4 waves; wave w handles query i = bx*4+w.
__global__ __launch_bounds__(256) void block_attn_kernel(
    const float* __restrict__ q, const float* __restrict__ kv, float* __restrict__ o)
{
  int h = blockIdx.y, lb = blockIdx.z;
  int t = threadIdx.x;
  int wave = t >> 6, lane = t & 63;
  int i = blockIdx.x * 4 + wave;

  __shared__ float Ks[192][65];   // 49,920 B (K, then reused for V)
  __shared__ float qs[4][64];
  __shared__ float ps[4][192];

  const float* kb = kv + (size_t)lb * 192 * 1024 + h * 64;
#pragma unroll
  for (int c = 0; c < 48; ++c) {
    int idx = c * 256 + t;
    int row = idx >> 6, col = idx & 63;
    Ks[row][col] = kb[(size_t)row * 1024 + col];
  }
  const float* qrow = q + ((size_t)(lb * 192 + i)) * 512 + h * 64;
  qs[wave][lane] = qrow[lane];
  __syncthreads();

  float s[3];
#pragma unroll
  for (int r = 0; r < 3; ++r) {
    int j = lane + r * 64;
    float acc = 0.f;
#pragma unroll 8
    for (int d = 0; d < 64; ++d) acc += qs[wave][d] * Ks[j][d];
    s[r] = acc;
  }
  float mx = fmaxf(fmaxf(s[0], s[1]), s[2]);
  for (int off = 32; off; off >>= 1) mx = fmaxf(mx, __shfl_xor(mx, off));
  float sum = 0.f;
#pragma unroll
  for (int r = 0; r < 3; ++r) { s[r] = expf(s[r] - mx); sum += s[r]; }
  for (int off = 32; off; off >>= 1) sum += __shfl_xor(sum, off);
  float inv = 1.f / sum;
#pragma unroll
  for (int r = 0; r < 3; ++r) ps[wave][lane + r * 64] = s[r] * inv;

  // ---- phase 2: stage V over K (all waves done with Ks), PV from LDS ----
  __syncthreads();
  const float* vb = kb + 512;
#pragma unroll
  for (int c = 0; c < 48; ++c) {
    int idx = c * 256 + t;
    int row = idx >> 6, col = idx & 63;
    Ks[row][col] = vb[(size_t)row * 1024 + col];
  }
  __syncthreads();
  float acc = 0.f;
  for (int j = 0; j < 192; ++j) acc += ps[wave][j] * Ks[j][lane];
  o[((size_t)(lb * 192 + i)) * 512 + h * 64 + lane] = acc;
}

// ================= pooled attention, K/V amortized over 6 queries ==========
__global__ __launch_bounds__(64) void pooled_attn_kernel(
    const float* __restrict__ q, const float* __restrict__ Kc,
    const float* __restrict__ Vc, float* __restrict__ o, int M, int mode)
{
  int n = blockIdx.x, h = blockIdx.y, z = blockIdx.z;
  int lane = threadIdx.x;
  int nq = mode ? 1 : 6;

  __shared__ float Ks[80][65];    // 20,800 B
  __shared__ float qs[6][64];
  __shared__ float p[6][128];

  for (int m = 0; m < M; ++m)
    Ks[m][lane] = Kc[(((size_t)m * 2 + z) * 192 + n) * 512 + h * 64 + lane];
  for (int jj = 0; jj < nq; ++jj) {
    const float* qrow = mode ? (q + h * 64)
                             : (q + ((size_t)((z * 6 + jj) * 192 + n)) * 512 + h * 64);
    qs[jj][lane] = qrow[lane];
  }
  __syncthreads();

  float d0[6] = {}, d1[6] = {};
  int m1 = lane + 64;
#pragma unroll 4
  for (int d = 0; d < 64; ++d) {
    float k0 = Ks[lane][d];
    float k1 = Ks[m1 & 79][d];
#pragma unroll
    for (int jj = 0; jj < 6; ++jj) {
      float qv = qs[jj][d];
      d0[jj] += qv * k0;
      d1[jj] += qv * k1;
    }
  }
  float acc[6] = {};
#pragma unroll
  for (int jj = 0; jj < 6; ++jj) {
    if (jj >= nq) break;
    float s0 = (lane < M) ? d0[jj] : -1e30f;
    float s1 = (m1 < M) ? d1[jj] : -1e30f;
    float mx = fmaxf(s0, s1);
    for (int off = 32; off; off >>= 1) mx = fmaxf(mx, __shfl_xor(mx, off));
    float e0 = (lane < M) ? expf(s0 - mx) : 0.f;
    float e1 = (m1 < M) ? expf(s1 - mx) : 0.f;
    float sum = e0 + e1;
    for (int off = 32; off; off >>= 1) sum += __shfl_xor(sum, off);
    float inv = 1.f / sum;
    p[jj][lane] = e0 * inv;
    p[jj][m1] = e1 * inv;
  }
  __syncthreads();

  for (int m = 0; m < M; ++m) {
    float v = Vc[(((size_t)m * 2 + z) * 192 + n) * 512 + h * 64 + lane];
#pragma unroll
    for (int jj = 0; jj < 6; ++jj) acc[jj] += p[jj][m] * v;
  }
#pragma unroll
  for (int jj = 0; jj < 6; ++jj) {
    if (jj >= nq) break;
    int orow = mode ? (z * 192 + n) : ((z * 6 + jj) * 192 + n);
    o[(size_t)orow * 512 + h * 64 + lane] = acc[jj];
  }
}

// ================= kv-cache fill (fp32, per-head key rmsnorm) ==============
__global__ __launch_bounds__(128) void cache_fill_kernel(
    const float* __restrict__ kvp, const float* __restrict__ knw,
    float* __restrict__ Kc, float* __restrict__ Vc, int base_e)
{
  int n = blockIdx.x;
  int t = blockIdx.y;
  int g = t >> 1, b = t & 1;
  int e = base_e + g;
  int lane = threadIdx.x;  // 128 lanes x 4 cols; 16 lanes per head
  const float* src = kvp + ((size_t)t * 192 + n) * 1024;
  float k4[4];
  float ss = 0.f;
#pragma unroll
  for (int u = 0; u < 4; ++u) { k4[u] = src[lane * 4 + u]; ss += k4[u] * k4[u]; }
  for (int off = 8; off; off >>= 1) ss += __shfl_xor(ss, off, 16);
  float rs = rsqrtf(ss * (1.f / 64.f) + EPSV);
  float* kd = Kc + (((size_t)e * 2 + b) * 192 + n) * 512;
  float* vd = Vc + (((size_t)e * 2 + b) * 192 + n) * 512;
#pragma unroll
  for (int u = 0; u < 4; ++u) {
    int c = lane * 4 + u;
    kd[c] = k4[u] * rs * knw[c & 63];
    vd[c] = src[512 + c];
  }
}

// ===========================================================================
extern "C" void kernel_launch(void* const* d_in, const int* in_sizes, int n_in,
                              void* d_out, int out_size, void* d_ws, size_t ws_size,
                              hipStream_t stream)
{
  const float* tokens   = (const float*)d_in[0];
  const float* attn_nw  = (const float*)d_in[1];
  const float* attn_qw  = (const float*)d_in[2];
  const float* attn_kvw = (const float*)d_in[3];
  const float* attn_ow  = (const float*)d_in[4];
  const float* ff_nw    = (const float*)d_in[5];
  const float* ff_kw    = (const float*)d_in[6];
  const float* ff_kb    = (const float*)d_in[7];
  const float* ff_vw    = (const float*)d_in[8];
  const float* ff_vb    = (const float*)d_in[9];
  const float* res_nw   = (const float*)d_in[10];
  const float* res_knw  = (const float*)d_in[11];
  const float* res_qw   = (const float*)d_in[12];
  const float* res_kvw  = (const float*)d_in[13];
  const float* res_ow   = (const float*)d_in[14];
  const float* q_ro     = (const float*)d_in[15];
  const float* ro_nw    = (const float*)d_in[16];
  const float* ro_w     = (const float*)d_in[17];
  float* out = (float*)d_out;

  // ---- workspace carve-up (54,281,728 floats = 217.1 MB) ----
  float* ws = (float*)d_ws;
  const size_t NEED = 54281728ull * 4ull;
  if (ws_size < NEED) return;
  float* ffk_w   = ws;  ws += 6ull * 2816 * 512;   // 8,650,752 (perm+pad fp32)
  float* ffk_b   = ws;  ws += 6ull * 2816;         // 16,896
  float* ffv_w   = ws;  ws += 6ull * 512 * 1408;   // 4,325,376 (K-pad fp32)
  float* toks    = ws;  ws += 1179648;             // [6,2,192,512]
  float* hbuf    = ws;  ws += 2359296;             // [<=4608,512]
  float* msgbuf  = ws;  ws += 2359296;             // [2,6,2,192,512]
  float* scratch = ws;  ws += 4718592;             // union region
  float* rqn     = ws;  ws += 512;
  float* rq      = ws;  ws += 512;
  float* Kc      = ws;  ws += 15335424;            // [78,2,192,512]
  float* Vc      = ws;  ws += 15335424;
  // scratch union (all uses strictly serialized on `stream`):
  float* qbuf   = scratch;                 // [2304,512]
  float* kvbuf  = scratch + 1179648;       // [12,192,1024]
  float* obuf   = scratch + 3538944;       // [2304,512]
  float* kvpool = scratch;                 // [<=24,192,1024] = 4,718,592
  float* act    = scratch;                 // [2304,1408] = 3,244,032
  // readout aliases (msgbuf dead by then):
  float* robuf  = msgbuf;                  // [384,512]
  float* robuf2 = msgbuf + 196608;         // [384,512]
  float* ronorm = msgbuf + 393216;         // [384,512]

  auto gemm = [&](const float* A, const float* W, const float* bias, float* C,
                  int M, int N, int K, int ldc,
                  long long aStr, long long wStr, long long bStr, long long cStr,
                  int nb, int mode) {
    int gx = (N + 127) / 128, gy = (M + 127) / 128;
    if (mode == 0 && gx * gy * nb <= 144) {
      dim3 g((N + 63) / 64, (M + 63) / 64, nb);
      hipLaunchKernelGGL((gemm_split_t<64, 2>), g, dim3(256), 0, stream,
                         A, W, bias, C, M, N, K, ldc, aStr, wStr, bStr, cStr, mode);
    } else {
      dim3 g(gx, gy, nb);
      hipLaunchKernelGGL((gemm_split_t<128, 4>), g, dim3(256), 0, stream,
                         A, W, bias, C, M, N, K, ldc, aStr, wStr, bStr, cStr, mode);
    }
  };

  // ---- FF weight prep (perm+pad) ----
  hipLaunchKernelGGL(ffk_perm_kernel, dim3((unsigned)((6ull * 2816 * 512 + 255) / 256)),
                     dim3(256), 0, stream, ff_kw, ff_kb, ffk_w, ffk_b);
  hipLaunchKernelGGL(ffv_pad_kernel, dim3((unsigned)((6ull * 512 * 1408 + 255) / 256)),
                     dim3(256), 0, stream, ff_vw, ffv_w);

  // ---- init: toks = broadcast(tokens); cache msg0 kv entries 0..5 ----
  {
    const int total = 6 * 2 * 192 * 512;
    hipLaunchKernelGGL(bcast_kernel, dim3((total + 255) / 256), dim3(256), 0, stream,
                       tokens, toks);
  }
  hipLaunchKernelGGL(rmsnorm_kernel, dim3(2304), dim3(256), 0, stream,
                     toks, res_nw, hbuf, 2304);
  gemm(hbuf, res_kvw, nullptr, kvpool, 384, 1024, 512, 1024,
       196608, 0, 0, 393216, 6, 0);
  hipLaunchKernelGGL(cache_fill_kernel, dim3(192, 12), dim3(128), 0, stream,
                     kvpool, res_knw, Kc, Vc, 0);

  for (int it = 0; it < 6; ++it) {
    // ---- block self-attention -> msgbuf[0] ----
    hipLaunchKernelGGL(rmsnorm_kernel, dim3(2304), dim3(256), 0, stream,
                       toks, attn_nw, hbuf, 384);
    gemm(hbuf, attn_qw, nullptr, qbuf, 384, 512, 512, 512,
         196608, 262144, 0, 196608, 6, 0);
    gemm(hbuf, attn_kvw, nullptr, kvbuf, 384, 1024, 512, 1024,
         196608, 524288, 0, 393216, 6, 0);
    hipLaunchKernelGGL(block_attn_kernel, dim3(48, 8, 12), dim3(256), 0, stream,
                       qbuf, kvbuf, obuf);
    gemm(obuf, attn_ow, nullptr, msgbuf, 384, 512, 512, 512,
         196608, 262144, 0, 196608, 6, 0);
    // ---- GEGLU FF (fused) -> msgbuf[1] ----
    hipLaunchKernelGGL(rmsnorm_kernel, dim3(2304), dim3(256), 0, stream,
                       toks, ff_nw, hbuf, 384);
    gemm(hbuf, ffk_w, ffk_b, act, 384, 2730, 512, 1408,
         196608, 1441792, 2816, 540672, 6, 1);       // clobbers qbuf/kvbuf (dead)
    gemm(act, ffv_w, ff_vb, msgbuf + 1179648, 384, 512, 1408, 512,
         540672, 720896, 512, 196608, 6, 0);
    // ---- cache kv for the two new messages ----
    hipLaunchKernelGGL(rmsnorm_kernel, dim3(4608), dim3(256), 0, stream,
                       msgbuf, res_nw, hbuf, 4608);
    gemm(hbuf, res_kvw, nullptr, kvpool, 384, 1024, 512, 1024,
         196608, 0, 0, 393216, 12, 0);               // clobbers act (dead)
    hipLaunchKernelGGL(cache_fill_kernel, dim3(192, 24), dim3(128), 0, stream,
                       kvpool, res_knw, Kc, Vc, (2 * it + 1) * 6);
    if (it == 5) break;
    // ---- pooled cross-attention over all cached entries -> new toks ----
    hipLaunchKernelGGL(rmsnorm_kernel, dim3(2304), dim3(256), 0, stream,
                       toks, res_nw, hbuf, 2304);
    gemm(hbuf, res_qw, nullptr, qbuf, 2304, 512, 512, 512,
         0, 0, 0, 0, 1, 0);                          // clobbers kvpool (dead)
    hipLaunchKernelGGL(pooled_attn_kernel, dim3(192, 8, 2), dim3(64), 0, stream,
                       qbuf, Kc, Vc, obuf, (3 + 2 * it) * 6, 0);
    gemm(obuf, res_ow, nullptr, toks, 2304, 512, 512, 512,
         0, 0, 0, 0, 1, 0);
  }

  // ---- readout ----
  hipLaunchKernelGGL(rmsnorm_kernel, dim3(1), dim3(256), 0, stream,
                     q_ro, res_nw, rqn, 1);
  gemm(rqn, res_qw, nullptr, rq, 1, 512, 512, 512, 0, 0, 0, 0, 1, 0);
  hipLaunchKernelGGL(pooled_attn_kernel, dim3(192, 8, 2), dim3(64), 0, stream,
                     rq, Kc, Vc, robuf, 78, 1);
  gemm(robuf, res_ow, nullptr, robuf2, 384, 512, 512, 512, 0, 0, 0, 0, 1, 0);
  hipLaunchKernelGGL(rmsnorm_kernel, dim3(384), dim3(256), 0, stream,
                     robuf2, ro_nw, ronorm, 384);
  gemm(ronorm, ro_w, nullptr, out, 384, 32000, 512, 32000, 0, 0, 0, 0, 1, 0);
}

// Round 13
// 1882.147 us; speedup vs baseline: 2.5423x; 1.0647x over previous
//
#include <hip/hip_runtime.h>
#include <hip/hip_bf16.h>
#include <math.h>

// ---------------------------------------------------------------------------
// DepthlessTransformer forward. Round 13 = round 12 (proven, 2004us) + two
// isolated, value-preserving changes:
//  (1) block_attn: 8 waves/block (grid 24,8,12, 512 thr). Same 58KB LDS ->
//      still 2 blocks/CU but 16 waves/CU (was 8); K+V staging amortized over
//      8 queries (was 4). Per-wave math identical. (r12 counters: occ 20.5%
//      capped by 4-wave blocks, VALU 34%.)
//  (2) rmsnorm2: attn-norm + ff-norm share the row rsqrt; one kernel writes
//      both outputs (6 fewer dispatches, half the toks re-reads).
// GEMM: split-at-staging hi/lo bf16 + reg-prefetch K-loop (r12-proven).
// D=512 H=8 DH=64 DI=512 L=6 NEX=6 FFI=1365 V=32000 B=2 N=192
// ---------------------------------------------------------------------------

#define EPSV 1.1920929e-07f
typedef __hip_bfloat16 bf16;
typedef __attribute__((ext_vector_type(4))) float f32x4;
typedef __attribute__((ext_vector_type(8))) short bf16x8;

// RTN split of 8 fp32 (two f32x4) into hi/lo bf16x8. Proven r5-12 numerics.
__device__ inline void split8r(f32x4 x0, f32x4 x1, bf16x8& h8, bf16x8& l8) {
#pragma unroll
  for (int i = 0; i < 4; ++i) {
    bf16 h0 = __float2bfloat16(x0[i]);
    h8[i] = __builtin_bit_cast(short, h0);
    l8[i] = __builtin_bit_cast(short, __float2bfloat16(x0[i] - __bfloat162float(h0)));
    bf16 h1 = __float2bfloat16(x1[i]);
    h8[i + 4] = __builtin_bit_cast(short, h1);
    l8[i + 4] = __builtin_bit_cast(short, __float2bfloat16(x1[i] - __bfloat162float(h1)));
  }
}

// ============== split-at-staging GEMM: C = A * W^T (+bias), fp32 in/out ====
// Template: BMN = square tile dim (128 or 64); MR = fragments per wave dim.
// LDS: hi/lo bf16 tiles, row pitch 40 bf16 (80B, 16B-aligned) -> 2-way banks.
// K-loop register-prefetches the next step's A/W (r12-proven).
// mode 0: plain (+optional bias). mode 1: GEGLU fused (interleaved rows).
#define BKG 32
#define LDB 40
template <int BMN, int MR>
__global__ __launch_bounds__(256) void gemm_split_t(
    const float* __restrict__ A, const float* __restrict__ W,
    const float* __restrict__ bias, float* __restrict__ C,
    int M, int N, int K, int ldc,
    long long aStr, long long wStr, long long bStr, long long cStr, int mode)
{
  int batch = blockIdx.z;
  A += (size_t)batch * aStr;
  W += (size_t)batch * wStr;
  C += (size_t)batch * cStr;
  if (bias) bias += (size_t)batch * bStr;
  int m0 = blockIdx.y * BMN, n0 = blockIdx.x * BMN;

  __shared__ short Ah[BMN * LDB], Al[BMN * LDB];
  __shared__ short Wh[BMN * LDB], Wl[BMN * LDB];

  int t = threadIdx.x;
  int wave = t >> 6, lane = t & 63;
  const int HALF = BMN / 2;
  const int NR = BMN / 64;                 // staged 64-row groups
  int wr = wave >> 1, wc = wave & 1;       // wave's HALFxHALF quadrant
  int fr = lane & 15, fq = lane >> 4;      // fragment row + k-group
  int srow = t >> 2;                       // staging rows r0+srow
  int scol = (t & 3) * 8;                  // float col 0,8,16,24

  f32x4 acc[MR][MR] = {};
  f32x4 pa0[NR], pa1[NR], pw0[NR], pw1[NR];

  // prologue: load K-step 0 into registers
#pragma unroll
  for (int r = 0; r < NR; ++r) {
    int row = r * 64 + srow;
    const float* pa = A + (size_t)(m0 + row) * K + scol;
    const float* pw = W + (size_t)(n0 + row) * K + scol;
    pa0[r] = *(const f32x4*)pa;  pa1[r] = *(const f32x4*)(pa + 4);
    pw0[r] = *(const f32x4*)pw;  pw1[r] = *(const f32x4*)(pw + 4);
  }

  for (int k0 = 0; k0 < K; k0 += BKG) {
    // ---- split + ds_write the CURRENT step from registers ----
#pragma unroll
    for (int r = 0; r < NR; ++r) {
      int row = r * 64 + srow;
      bf16x8 h, l;
      split8r(pa0[r], pa1[r], h, l);
      *(bf16x8*)&Ah[row * LDB + scol] = h;
      *(bf16x8*)&Al[row * LDB + scol] = l;
      split8r(pw0[r], pw1[r], h, l);
      *(bf16x8*)&Wh[row * LDB + scol] = h;
      *(bf16x8*)&Wl[row * LDB + scol] = l;
    }
    // ---- issue NEXT step's global loads (consumed after next barrier) ----
    if (k0 + BKG < K) {
      int kn = k0 + BKG;
#pragma unroll
      for (int r = 0; r < NR; ++r) {
        int row = r * 64 + srow;
        const float* pa = A + (size_t)(m0 + row) * K + kn + scol;
        const float* pw = W + (size_t)(n0 + row) * K + kn + scol;
        pa0[r] = *(const f32x4*)pa;  pa1[r] = *(const f32x4*)(pa + 4);
        pw0[r] = *(const f32x4*)pw;  pw1[r] = *(const f32x4*)(pw + 4);
      }
    }
    __syncthreads();
    bf16x8 ah[MR], al[MR], wh[MR], wl[MR];
#pragma unroll
    for (int m = 0; m < MR; ++m) {
      int r = (wr * HALF + m * 16 + fr) * LDB + fq * 8;
      ah[m] = *(const bf16x8*)&Ah[r];
      al[m] = *(const bf16x8*)&Al[r];
    }
#pragma unroll
    for (int n = 0; n < MR; ++n) {
      int r = (wc * HALF + n * 16 + fr) * LDB + fq * 8;
      wh[n] = *(const bf16x8*)&Wh[r];
      wl[n] = *(const bf16x8*)&Wl[r];
    }
#pragma unroll
    for (int m = 0; m < MR; ++m)
#pragma unroll
      for (int n = 0; n < MR; ++n) {
        acc[m][n] = __builtin_amdgcn_mfma_f32_16x16x32_bf16(ah[m], wh[n], acc[m][n], 0, 0, 0);
        acc[m][n] = __builtin_amdgcn_mfma_f32_16x16x32_bf16(al[m], wh[n], acc[m][n], 0, 0, 0);
        acc[m][n] = __builtin_amdgcn_mfma_f32_16x16x32_bf16(ah[m], wl[n], acc[m][n], 0, 0, 0);
      }
    __syncthreads();
  }

  if (mode == 0) {
#pragma unroll
    for (int m = 0; m < MR; ++m)
#pragma unroll
      for (int n = 0; n < MR; ++n) {
        int col = n0 + wc * HALF + n * 16 + fr;
        if (col >= N) continue;
        float bv = bias ? bias[col] : 0.f;
#pragma unroll
        for (int j = 0; j < 4; ++j) {
          int row = m0 + wr * HALF + m * 16 + fq * 4 + j;
          if (row < M) C[(size_t)row * ldc + col] = acc[m][n][j] + bv;
        }
      }
  } else {
    // GEGLU: even col = sim, odd col = gate (interleaved weight rows).
#pragma unroll
    for (int m = 0; m < MR; ++m)
#pragma unroll
      for (int n = 0; n < MR; ++n) {
        int col = n0 + wc * HALF + n * 16 + fr;
        float bv = bias[col];
#pragma unroll
        for (int j = 0; j < 4; ++j) {
          float z = acc[m][n][j] + bv;
          float zn = __shfl_xor(z, 1);   // partner: sim<->gate
          if (!(col & 1) && col < N) {
            float g = zn;
            float a = z * (0.5f * g * (1.f + erff(g * 0.70710678118654752f)));
            int row = m0 + wr * HALF + m * 16 + fq * 4 + j;
            if (row < M) C[(size_t)row * ldc + (col >> 1)] = a;
          }
        }
      }
  }
}

// ====== FF-keys weight perm+pad: [6,2730,512] -> [6,2816,512] interleaved ==
__global__ void ffk_perm_kernel(const float* __restrict__ kw,
                                const float* __restrict__ kb,
                                float* __restrict__ wout, float* __restrict__ bout)
{
  size_t idx = (size_t)blockIdx.x * 256 + threadIdx.x;
  const size_t per = 2816ull * 512;
  if (idx < 6 * per) {
    int b = (int)(idx / per);
    size_t r2 = idx % per;
    int r = (int)(r2 >> 9), k = (int)(r2 & 511);
    float v = 0.f;
    if (r < 2730) {
      int c = (r >> 1) + (r & 1) * 1365;
      v = kw[((size_t)b * 2730 + c) * 512 + k];
    }
    wout[idx] = v;
  }
  if (idx < 6 * 2816) {
    int b = (int)(idx / 2816), r = (int)(idx % 2816);
    float v = 0.f;
    if (r < 2730) {
      int c = (r >> 1) + (r & 1) * 1365;
      v = kb[(size_t)b * 2730 + c];
    }
    bout[idx] = v;
  }
}

// ====== FF-vals weight pad: [6,512,1365] -> [6,512,1408] (K zero-pad) ======
__global__ void ffv_pad_kernel(const float* __restrict__ vw, float* __restrict__ wout)
{
  size_t idx = (size_t)blockIdx.x * 256 + threadIdx.x;
  const size_t total = 6ull * 512 * 1408;
  if (idx >= total) return;
  int k = (int)(idx % 1408);
  size_t nr = idx / 1408;   // b*512 + n
  wout[idx] = (k < 1365) ? vw[nr * 1365 + k] : 0.f;
}

// ================= rmsnorm over dim 512 (fp32 -> fp32) =====================
__global__ __launch_bounds__(256) void rmsnorm_kernel(
    const float* __restrict__ x, const float* __restrict__ w,
    float* __restrict__ out, int rows_per_w)
{
  int r = blockIdx.x;
  int t = threadIdx.x;
  const float* xr = x + (size_t)r * 512;
  float a = xr[t], b = xr[t + 256];
  float ss = a * a + b * b;
  for (int off = 32; off; off >>= 1) ss += __shfl_xor(ss, off);
  __shared__ float wsum[4];
  if ((t & 63) == 0) wsum[t >> 6] = ss;
  __syncthreads();
  float tot = wsum[0] + wsum[1] + wsum[2] + wsum[3];
  float rs = rsqrtf(tot * (1.f / 512.f) + EPSV);
  const float* wr = w + (size_t)(r / rows_per_w) * 512;
  out[(size_t)r * 512 + t] = a * rs * wr[t];
  out[(size_t)r * 512 + t + 256] = b * rs * wr[t + 256];
}

// ======== dual-output rmsnorm: same row stats, two weights/outputs =========
__global__ __launch_bounds__(256) void rmsnorm2_kernel(
    const float* __restrict__ x, const float* __restrict__ w1,
    const float* __restrict__ w2, float* __restrict__ o1,
    float* __restrict__ o2, int rows_per_w)
{
  int r = blockIdx.x;
  int t = threadIdx.x;
  const float* xr = x + (size_t)r * 512;
  float a = xr[t], b = xr[t + 256];
  float ss = a * a + b * b;
  for (int off = 32; off; off >>= 1) ss += __shfl_xor(ss, off);
  __shared__ float wsum[4];
  if ((t & 63) == 0) wsum[t >> 6] = ss;
  __syncthreads();
  float tot = wsum[0] + wsum[1] + wsum[2] + wsum[3];
  float rs = rsqrtf(tot * (1.f / 512.f) + EPSV);
  int wrow = r / rows_per_w;
  float ar = a * rs, br = b * rs;
  o1[(size_t)r * 512 + t]       = ar * w1[(size_t)wrow * 512 + t];
  o1[(size_t)r * 512 + t + 256] = br * w1[(size_t)wrow * 512 + t + 256];
  o2[(size_t)r * 512 + t]       = ar * w2[(size_t)wrow * 512 + t];
  o2[(size_t)r * 512 + t + 256] = br * w2[(size_t)wrow * 512 + t + 256];
}

// ================= broadcast tokens -> toks[L] =============================
__global__ void bcast_kernel(const float* __restrict__ tokens, float* __restrict__ toks)
{
  size_t idx = (size_t)blockIdx.x * 256 + threadIdx.x;
  const size_t total = (size_t)6 * 2 * 192 * 512;
  if (idx >= total) return;
  toks[idx] = tokens[idx % ((size_t)2 * 192 * 512)];
}

// ================= block self-attention, LDS-staged K then V, 8 waves ======
// grid (24, 8, 12), 512 threads = 8 waves; wave w handles query i = bx*8+w.
__global__ __launch_bounds__(512) void block_attn_kernel(
    const float* __restrict__ q, const float* __restrict__ kv, float* __restrict__ o)
{
  int h = blockIdx.y, lb = blockIdx.z;
  int t = threadIdx.x;
  int wave = t >> 6, lane = t & 63;
  int i = blockIdx.x * 8 + wave;

  __shared__ float Ks[192][65];   // 49,920 B (K, then reused for V)
  __shared__ float qs[8][64];
  __shared__ float ps[8][192];

  const float* kb = kv + (size_t)lb * 192 * 1024 + h * 64;
#pragma unroll
  for (int c = 0; c < 24; ++c) {
    int idx = c * 512 + t;
    int row = idx >> 6, col = idx & 63;
    Ks[row][col] = kb[(size_t)row * 1024 + col];
  }
  const float* qrow = q + ((size_t)(lb * 192 + i)) * 512 + h * 64;
  qs[wave][lane] = qrow[lane];
  __syncthreads();

  float s[3];
#pragma unroll
  for (int r = 0; r < 3; ++r) {
    int j = lane + r * 64;
    float acc = 0.f;
#pragma unroll 8
    for (int d = 0; d < 64; ++d) acc += qs[wave][d] * Ks[j][d];
    s[r] = acc;
  }
  float mx = fmaxf(fmaxf(s[0], s[1]), s[2]);
  for (int off = 32; off; off >>= 1) mx = fmaxf(mx, __shfl_xor(mx, off));
  float sum = 0.f;
#pragma unroll
  for (int r = 0; r < 3; ++r) { s[r] = expf(s[r] - mx); sum += s[r]; }
  for (int off = 32; off; off >>= 1) sum += __shfl_xor(sum, off);
  float inv = 1.f / sum;
#pragma unroll
  for (int r = 0; r < 3; ++r) ps[wave][lane + r * 64] = s[r] * inv;

  // ---- phase 2: stage V over K (all waves done with Ks), PV from LDS ----
  __syncthreads();
  const float* vb = kb + 512;
#pragma unroll
  for (int c = 0; c < 24; ++c) {
    int idx = c * 512 + t;
    int row = idx >> 6, col = idx & 63;
    Ks[row][col] = vb[(size_t)row * 1024 + col];
  }
  __syncthreads();
  float acc = 0.f;
  for (int j = 0; j < 192; ++j) acc += ps[wave][j] * Ks[j][lane];
  o[((size_t)(lb * 192 + i)) * 512 + h * 64 + lane] = acc;
}

// ================= pooled attention, K/V amortized over 6 queries ==========
__global__ __launch_bounds__(64) void pooled_attn_kernel(
    const float* __restrict__ q, const float* __restrict__ Kc,
    const float* __restrict__ Vc, float* __restrict__ o, int M, int mode)
{
  int n = blockIdx.x, h = blockIdx.y, z = blockIdx.z;
  int lane = threadIdx.x;
  int nq = mode ? 1 : 6;

  __shared__ float Ks[80][65];    // 20,800 B
  __shared__ float qs[6][64];
  __shared__ float p[6][128];

  for (int m = 0; m < M; ++m)
    Ks[m][lane] = Kc[(((size_t)m * 2 + z) * 192 + n) * 512 + h * 64 + lane];
  for (int jj = 0; jj < nq; ++jj) {
    const float* qrow = mode ? (q + h * 64)
                             : (q + ((size_t)((z * 6 + jj) * 192 + n)) * 512 + h * 64);
    qs[jj][lane] = qrow[lane];
  }
  __syncthreads();

  float d0[6] = {}, d1[6] = {};
  int m1 = lane + 64;
#pragma unroll 4
  for (int d = 0; d < 64; ++d) {
    float k0 = Ks[lane][d];
    float k1 = Ks[m1 & 79][d];
#pragma unroll
    for (int jj = 0; jj < 6; ++jj) {
      float qv = qs[jj][d];
      d0[jj] += qv * k0;
      d1[jj] += qv * k1;
    }
  }
  float acc[6] = {};
#pragma unroll
  for (int jj = 0; jj < 6; ++jj) {
    if (jj >= nq) break;
    float s0 = (lane < M) ? d0[jj] : -1e30f;
    float s1 = (m1 < M) ? d1[jj] : -1e30f;
    float mx = fmaxf(s0, s1);
    for (int off = 32; off; off >>= 1) mx = fmaxf(mx, __shfl_xor(mx, off));
    float e0 = (lane < M) ? expf(s0 - mx) : 0.f;
    float e1 = (m1 < M) ? expf(s1 - mx) : 0.f;
    float sum = e0 + e1;
    for (int off = 32; off; off >>= 1) sum += __shfl_xor(sum, off);
    float inv = 1.f / sum;
    p[jj][lane] = e0 * inv;
    p[jj][m1] = e1 * inv;
  }
  __syncthreads();

  for (int m = 0; m < M; ++m) {
    float v = Vc[(((size_t)m * 2 + z) * 192 + n) * 512 + h * 64 + lane];
#pragma unroll
    for (int jj = 0; jj < 6; ++jj) acc[jj] += p[jj][m] * v;
  }
#pragma unroll
  for (int jj = 0; jj < 6; ++jj) {
    if (jj >= nq) break;
    int orow = mode ? (z * 192 + n) : ((z * 6 + jj) * 192 + n);
    o[(size_t)orow * 512 + h * 64 + lane] = acc[jj];
  }
}

// ================= kv-cache fill (fp32, per-head key rmsnorm) ==============
__global__ __launch_bounds__(128) void cache_fill_kernel(
    const float* __restrict__ kvp, const float* __restrict__ knw,
    float* __restrict__ Kc, float* __restrict__ Vc, int base_e)
{
  int n = blockIdx.x;
  int t = blockIdx.y;
  int g = t >> 1, b = t & 1;
  int e = base_e + g;
  int lane = threadIdx.x;  // 128 lanes x 4 cols; 16 lanes per head
  const float* src = kvp + ((size_t)t * 192 + n) * 1024;
  float k4[4];
  float ss = 0.f;
#pragma unroll
  for (int u = 0; u < 4; ++u) { k4[u] = src[lane * 4 + u]; ss += k4[u] * k4[u]; }
  for (int off = 8; off; off >>= 1) ss += __shfl_xor(ss, off, 16);
  float rs = rsqrtf(ss * (1.f / 64.f) + EPSV);
  float* kd = Kc + (((size_t)e * 2 + b) * 192 + n) * 512;
  float* vd = Vc + (((size_t)e * 2 + b) * 192 + n) * 512;
#pragma unroll
  for (int u = 0; u < 4; ++u) {
    int c = lane * 4 + u;
    kd[c] = k4[u] * rs * knw[c & 63];
    vd[c] = src[512 + c];
  }
}

// ===========================================================================
extern "C" void kernel_launch(void* const* d_in, const int* in_sizes, int n_in,
                              void* d_out, int out_size, void* d_ws, size_t ws_size,
                              hipStream_t stream)
{
  const float* tokens   = (const float*)d_in[0];
  const float* attn_nw  = (const float*)d_in[1];
  const float* attn_qw  = (const float*)d_in[2];
  const float* attn_kvw = (const float*)d_in[3];
  const float* attn_ow  = (const float*)d_in[4];
  const float* ff_nw    = (const float*)d_in[5];
  const float* ff_kw    = (const float*)d_in[6];
  const float* ff_kb    = (const float*)d_in[7];
  const float* ff_vw    = (const float*)d_in[8];
  const float* ff_vb    = (const float*)d_in[9];
  const float* res_nw   = (const float*)d_in[10];
  const float* res_knw  = (const float*)d_in[11];
  const float* res_qw   = (const float*)d_in[12];
  const float* res_kvw  = (const float*)d_in[13];
  const float* res_ow   = (const float*)d_in[14];
  const float* q_ro     = (const float*)d_in[15];
  const float* ro_nw    = (const float*)d_in[16];
  const float* ro_w     = (const float*)d_in[17];
  float* out = (float*)d_out;

  // ---- workspace carve-up (54,281,728 floats = 217.1 MB) ----
  float* ws = (float*)d_ws;
  const size_t NEED = 54281728ull * 4ull;
  if (ws_size < NEED) return;
  float* ffk_w   = ws;  ws += 6ull * 2816 * 512;   // 8,650,752 (perm+pad fp32)
  float* ffk_b   = ws;  ws += 6ull * 2816;         // 16,896
  float* ffv_w   = ws;  ws += 6ull * 512 * 1408;   // 4,325,376 (K-pad fp32)
  float* toks    = ws;  ws += 1179648;             // [6,2,192,512]
  float* hbuf    = ws;  ws += 2359296;             // [<=4608,512]
  float* msgbuf  = ws;  ws += 2359296;             // [2,6,2,192,512]
  float* scratch = ws;  ws += 4718592;             // union region
  float* rqn     = ws;  ws += 512;
  float* rq      = ws;  ws += 512;
  float* Kc      = ws;  ws += 15335424;            // [78,2,192,512]
  float* Vc      = ws;  ws += 15335424;
  // scratch union (all uses strictly serialized on `stream`):
  float* qbuf   = scratch;                 // [2304,512]
  float* kvbuf  = scratch + 1179648;       // [12,192,1024]
  float* obuf   = scratch + 3538944;       // [2304,512]
  float* kvpool = scratch;                 // [<=24,192,1024] = 4,718,592
  float* act    = scratch;                 // [2304,1408] = 3,244,032
  float* hbuf2  = hbuf + 1179648;          // ff-normed rows (dead before 4608-row rmsnorm)
  // readout aliases (msgbuf dead by then):
  float* robuf  = msgbuf;                  // [384,512]
  float* robuf2 = msgbuf + 196608;         // [384,512]
  float* ronorm = msgbuf + 393216;         // [384,512]

  auto gemm = [&](const float* A, const float* W, const float* bias, float* C,
                  int M, int N, int K, int ldc,
                  long long aStr, long long wStr, long long bStr, long long cStr,
                  int nb, int mode) {
    int gx = (N + 127) / 128, gy = (M + 127) / 128;
    if (mode == 0 && gx * gy * nb <= 144) {
      dim3 g((N + 63) / 64, (M + 63) / 64, nb);
      hipLaunchKernelGGL((gemm_split_t<64, 2>), g, dim3(256), 0, stream,
                         A, W, bias, C, M, N, K, ldc, aStr, wStr, bStr, cStr, mode);
    } else {
      dim3 g(gx, gy, nb);
      hipLaunchKernelGGL((gemm_split_t<128, 4>), g, dim3(256), 0, stream,
                         A, W, bias, C, M, N, K, ldc, aStr, wStr, bStr, cStr, mode);
    }
  };

  // ---- FF weight prep (perm+pad) ----
  hipLaunchKernelGGL(ffk_perm_kernel, dim3((unsigned)((6ull * 2816 * 512 + 255) / 256)),
                     dim3(256), 0, stream, ff_kw, ff_kb, ffk_w, ffk_b);
  hipLaunchKernelGGL(ffv_pad_kernel, dim3((unsigned)((6ull * 512 * 1408 + 255) / 256)),
                     dim3(256), 0, stream, ff_vw, ffv_w);

  // ---- init: toks = broadcast(tokens); cache msg0 kv entries 0..5 ----
  {
    const int total = 6 * 2 * 192 * 512;
    hipLaunchKernelGGL(bcast_kernel, dim3((total + 255) / 256), dim3(256), 0, stream,
                       tokens, toks);
  }
  hipLaunchKernelGGL(rmsnorm_kernel, dim3(2304), dim3(256), 0, stream,
                     toks, res_nw, hbuf, 2304);
  gemm(hbuf, res_kvw, nullptr, kvpool, 384, 1024, 512, 1024,
       196608, 0, 0, 393216, 6, 0);
  hipLaunchKernelGGL(cache_fill_kernel, dim3(192, 12), dim3(128), 0, stream,
                     kvpool, res_knw, Kc, Vc, 0);

  for (int it = 0; it < 6; ++it) {
    // ---- norms for both branches (shared row stats) ----
    hipLaunchKernelGGL(rmsnorm2_kernel, dim3(2304), dim3(256), 0, stream,
                       toks, attn_nw, ff_nw, hbuf, hbuf2, 384);
    // ---- block self-attention -> msgbuf[0] ----
    gemm(hbuf, attn_qw, nullptr, qbuf, 384, 512, 512, 512,
         196608, 262144, 0, 196608, 6, 0);
    gemm(hbuf, attn_kvw, nullptr, kvbuf, 384, 1024, 512, 1024,
         196608, 524288, 0, 393216, 6, 0);
    hipLaunchKernelGGL(block_attn_kernel, dim3(24, 8, 12), dim3(512), 0, stream,
                       qbuf, kvbuf, obuf);
    gemm(obuf, attn_ow, nullptr, msgbuf, 384, 512, 512, 512,
         196608, 262144, 0, 196608, 6, 0);
    // ---- GEGLU FF (fused) -> msgbuf[1] ----
    gemm(hbuf2, ffk_w, ffk_b, act, 384, 2730, 512, 1408,
         196608, 1441792, 2816, 540672, 6, 1);       // clobbers qbuf/kvbuf (dead)
    gemm(act, ffv_w, ff_vb, msgbuf + 1179648, 384, 512, 1408, 512,
         540672, 720896, 512, 196608, 6, 0);
    // ---- cache kv for the two new messages ----
    hipLaunchKernelGGL(rmsnorm_kernel, dim3(4608), dim3(256), 0, stream,
                       msgbuf, res_nw, hbuf, 4608);
    gemm(hbuf, res_kvw, nullptr, kvpool, 384, 1024, 512, 1024,
         196608, 0, 0, 393216, 12, 0);               // clobbers act (dead)
    hipLaunchKernelGGL(cache_fill_kernel, dim3(192, 24), dim3(128), 0, stream,
                       kvpool, res_knw, Kc, Vc, (2 * it + 1) * 6);
    if (it == 5) break;
    // ---- pooled cross-attention over all cached entries -> new toks ----
    hipLaunchKernelGGL(rmsnorm_kernel, dim3(2304), dim3(256), 0, stream,
                       toks, res_nw, hbuf, 2304);
    gemm(hbuf, res_qw, nullptr, qbuf, 2304, 512, 512, 512,
         0, 0, 0, 0, 1, 0);                          // clobbers kvpool (dead)
    hipLaunchKernelGGL(pooled_attn_kernel, dim3(192, 8, 2), dim3(64), 0, stream,
                       qbuf, Kc, Vc, obuf, (3 + 2 * it) * 6, 0);
    gemm(obuf, res_ow, nullptr, toks, 2304, 512, 512, 512,
         0, 0, 0, 0, 1, 0);
  }

  // ---- readout ----
  hipLaunchKernelGGL(rmsnorm_kernel, dim3(1), dim3(256), 0, stream,
                     q_ro, res_nw, rqn, 1);
  gemm(rqn, res_qw, nullptr, rq, 1, 512, 512, 512, 0, 0, 0, 0, 1, 0);
  hipLaunchKernelGGL(pooled_attn_kernel, dim3(192, 8, 2), dim3(64), 0, stream,
                     rq, Kc, Vc, robuf, 78, 1);
  gemm(robuf, res_ow, nullptr, robuf2, 384, 512, 512, 512, 0, 0, 0, 0, 1, 0);
  hipLaunchKernelGGL(rmsnorm_kernel, dim3(384), dim3(256), 0, stream,
                     robuf2, ro_nw, ronorm, 384);
  gemm(ronorm, ro_w, nullptr, out, 384, 32000, 512, 32000, 0, 0, 0, 0, 1, 0);
}